// Round 4
// baseline (302.355 us; speedup 1.0000x reference)
//
#include <hip/hip_runtime.h>
#include <hip/hip_bf16.h>

using bf16x8 = __attribute__((ext_vector_type(8))) short;
using f32x4  = __attribute__((ext_vector_type(4))) float;

__device__ __forceinline__ short f2bf(float f) {
  union { float f; unsigned u; } v; v.f = f;
  unsigned r = (v.u + 0x7FFFu + ((v.u >> 16) & 1u)) >> 16;
  return (short)(unsigned short)r;
}

// pack two f32 -> two bf16 (RNE) in one HW op
__device__ __forceinline__ unsigned cvtpk(float lo, float hi) {
  unsigned r;
  asm("v_cvt_pk_bf16_f32 %0, %1, %2" : "=v"(r) : "v"(lo), "v"(hi));
  return r;
}

// load 8 consecutive fp32 and round to bf16x8
__device__ __forceinline__ bf16x8 ld8f(const float* __restrict__ p) {
  float4 lo = *(const float4*)p;
  float4 hi = *(const float4*)(p + 4);
  bf16x8 r;
  r[0] = f2bf(lo.x); r[1] = f2bf(lo.y); r[2] = f2bf(lo.z); r[3] = f2bf(lo.w);
  r[4] = f2bf(hi.x); r[5] = f2bf(hi.y); r[6] = f2bf(hi.z); r[7] = f2bf(hi.w);
  return r;
}

#define BM 128
#define BN 128
#define BKSTEP 32
#define LDK 40   // 32 + 8 pad elems; 80B row stride

// C = A[M,K] * B[N,K]^T, A/B fp32 (converted to bf16 for MFMA).
// MODE 0: fp32 C to outC.
// MODE 1: QKV epilogue — l2norm q,k rows, temp*log2e folded into q,
//         scatter bf16 Q[b,h,n,d], K[b,h,n,d], Vt[b,h,d,n].
template<int MODE>
__global__ __launch_bounds__(256, 2)
void gemm_bt(const float* __restrict__ A, const float* __restrict__ B,
             short* __restrict__ outQ, short* __restrict__ outK, short* __restrict__ outVt,
             float* __restrict__ outC,
             const float* __restrict__ temp,
             int M, int N, int Kd)
{
  __shared__ short As[BM * LDK];
  __shared__ short Bs[BN * LDK];
  const int tid  = threadIdx.x;
  const int lane = tid & 63;
  const int w    = tid >> 6;
  const int wr   = w >> 1, wc = w & 1;
  const int fr   = lane & 15, fq = lane >> 4;
  const int bm = blockIdx.y, bn = blockIdx.x;
  const int rowA = bm * BM, rowB = bn * BN;
  const int sr = tid >> 2;
  const int sc = (tid & 3) * 8;

  f32x4 acc[4][4];
  #pragma unroll
  for (int m = 0; m < 4; ++m)
    #pragma unroll
    for (int n = 0; n < 4; ++n) acc[m][n] = (f32x4){0.f, 0.f, 0.f, 0.f};

  for (int k0 = 0; k0 < Kd; k0 += BKSTEP) {
    bf16x8 a0 = ld8f(A + (size_t)(rowA + sr)      * Kd + k0 + sc);
    bf16x8 a1 = ld8f(A + (size_t)(rowA + 64 + sr) * Kd + k0 + sc);
    bf16x8 b0 = ld8f(B + (size_t)(rowB + sr)      * Kd + k0 + sc);
    bf16x8 b1 = ld8f(B + (size_t)(rowB + 64 + sr) * Kd + k0 + sc);
    __syncthreads();   // WAR: previous iter's frag reads done before overwrite
    *(bf16x8*)(As + sr * LDK + sc)        = a0;
    *(bf16x8*)(As + (64 + sr) * LDK + sc) = a1;
    *(bf16x8*)(Bs + sr * LDK + sc)        = b0;
    *(bf16x8*)(Bs + (64 + sr) * LDK + sc) = b1;
    __syncthreads();
    bf16x8 afr[4], bfr[4];
    #pragma unroll
    for (int m = 0; m < 4; ++m)
      afr[m] = *(const bf16x8*)(As + (wr*64 + m*16 + fr) * LDK + fq*8);
    #pragma unroll
    for (int n = 0; n < 4; ++n)
      bfr[n] = *(const bf16x8*)(Bs + (wc*64 + n*16 + fr) * LDK + fq*8);
    #pragma unroll
    for (int m = 0; m < 4; ++m)
      #pragma unroll
      for (int n = 0; n < 4; ++n)
        acc[m][n] = __builtin_amdgcn_mfma_f32_16x16x32_bf16(afr[m], bfr[n], acc[m][n], 0, 0, 0);
  }

  if (MODE == 0) {
    #pragma unroll
    for (int m = 0; m < 4; ++m) {
      int r0 = rowA + wr*64 + m*16 + fq*4;
      #pragma unroll
      for (int n = 0; n < 4; ++n) {
        int c = rowB + wc*64 + n*16 + fr;
        #pragma unroll
        for (int r = 0; r < 4; ++r)
          outC[(size_t)(r0 + r) * N + c] = acc[m][n][r];
      }
    }
  } else {
    const int gc0   = rowB + wc*64;
    const int slice = gc0 >> 6;      // 0..23
    const int t3    = slice >> 3;    // 0=q,1=k,2=v
    const int h     = slice & 7;
    if (t3 < 2) {
      float scl[4][4];
      // fold log2(e) into q so attention can use native exp2
      const float tval = (t3 == 0) ? temp[h] * 1.44269504088896f : 1.0f;
      #pragma unroll
      for (int m = 0; m < 4; ++m) {
        #pragma unroll
        for (int r = 0; r < 4; ++r) {
          float ss = 0.f;
          #pragma unroll
          for (int n = 0; n < 4; ++n) ss += acc[m][n][r] * acc[m][n][r];
          #pragma unroll
          for (int off = 1; off < 16; off <<= 1) ss += __shfl_xor(ss, off);
          scl[m][r] = tval / fmaxf(sqrtf(ss), 1e-12f);
        }
      }
      short* dst = (t3 == 0) ? outQ : outK;
      #pragma unroll
      for (int m = 0; m < 4; ++m) {
        #pragma unroll
        for (int r = 0; r < 4; ++r) {
          int rg = rowA + wr*64 + m*16 + fq*4 + r;
          int b = rg >> 11, nn = rg & 2047;
          size_t rowoff = ((size_t)(b*8 + h) * 2048 + nn) * 64;
          #pragma unroll
          for (int n = 0; n < 4; ++n)
            dst[rowoff + n*16 + fr] = f2bf(acc[m][n][r] * scl[m][r]);
        }
      }
    } else {
      #pragma unroll
      for (int m = 0; m < 4; ++m) {
        #pragma unroll
        for (int r = 0; r < 4; ++r) {
          int rg = rowA + wr*64 + m*16 + fq*4 + r;
          int b = rg >> 11, nn = rg & 2047;
          #pragma unroll
          for (int n = 0; n < 4; ++n)
            outVt[((size_t)(b*8 + h) * 64 + n*16 + fr) * 2048 + nn] = f2bf(acc[m][n][r]);
        }
      }
    }
  }
}

#define LDP 72   // 16x64 P tile padded: 144B row stride (16B aligned)

// Flash attention, swapped-QK^T layout. Scores arrive pre-scaled by log2e
// (folded into Q), so softmax uses native exp2.
// blockIdx.x = bh  => XCD (linear%8) is determined by bh: each XCD's L2
// serves only 4 heads' K/V (2MB, fits 4MB L2) shared by its 32 q-tiles.
__global__ __launch_bounds__(256, 4)
void attn_fwd(const short* __restrict__ Q, const short* __restrict__ Kt,
              const short* __restrict__ Vt, float* __restrict__ AO)
{
  __shared__ short Pl[4][16 * LDP];
  const int tid  = threadIdx.x;
  const int lane = tid & 63;
  const int w    = tid >> 6;
  const int fr   = lane & 15, fq = lane >> 4;
  const int bh = blockIdx.x;          // b*8+h  -> XCD = bh%8
  const int qt = blockIdx.y;          // q tile of 64
  const int b = bh >> 3, h = bh & 7;
  const size_t base  = (size_t)bh * 2048 * 64;  // Q,K: [bh][n][64]
  const size_t vbase = (size_t)bh * 64 * 2048;  // Vt:  [bh][64][n]
  const int q0 = qt * 64 + w * 16;

  // Q fragment (B-operand): lane holds Q row q0+fr, d-elems fq*8..+7 (+32)
  bf16x8 bq[2];
  #pragma unroll
  for (int j = 0; j < 2; ++j)
    bq[j] = *(const bf16x8*)(Q + base + (size_t)(q0 + fr) * 64 + j*32 + fq*8);

  f32x4 o[4];
  #pragma unroll
  for (int db = 0; db < 4; ++db) o[db] = (f32x4){0.f, 0.f, 0.f, 0.f};
  float mrun = -1e30f;   // running max (log2 units) for q = q0+fr
  float lrun = 0.f;      // running denom for q = q0+fr

  short* pw = &Pl[w][0];
  const short* kp = Kt + base;
  const short* vp = Vt + vbase;

  for (int t = 0; t < 32; ++t) {
    const int k0 = t * 64;
    // S^T tiles: A = K rows (k), B = Q rows (q).
    // Lane holds s[nb][r] = S[q=q0+fr][k = k0 + nb*16 + fq*4 + r] (log2 units)
    f32x4 s[4];
    #pragma unroll
    for (int nb = 0; nb < 4; ++nb) {
      bf16x8 ak0 = *(const bf16x8*)(kp + (size_t)(k0 + nb*16 + fr) * 64 + fq*8);
      bf16x8 ak1 = *(const bf16x8*)(kp + (size_t)(k0 + nb*16 + fr) * 64 + 32 + fq*8);
      f32x4 z = (f32x4){0.f, 0.f, 0.f, 0.f};
      z = __builtin_amdgcn_mfma_f32_16x16x32_bf16(ak0, bq[0], z, 0, 0, 0);
      z = __builtin_amdgcn_mfma_f32_16x16x32_bf16(ak1, bq[1], z, 0, 0, 0);
      s[nb] = z;
    }
    // issue V loads NOW: softmax + P LDS roundtrip hides their L2 latency
    bf16x8 bv[4][2];
    #pragma unroll
    for (int db = 0; db < 4; ++db) {
      bv[db][0] = *(const bf16x8*)(vp + (size_t)(db*16 + fr) * 2048 + k0 + fq*8);
      bv[db][1] = *(const bf16x8*)(vp + (size_t)(db*16 + fr) * 2048 + k0 + 32 + fq*8);
    }
    // tile max (in-lane over 16, then across the 4 fq replicas of this q)
    float mx = s[0][0];
    #pragma unroll
    for (int nb = 0; nb < 4; ++nb)
      #pragma unroll
      for (int r = 0; r < 4; ++r) mx = fmaxf(mx, s[nb][r]);
    mx = fmaxf(mx, __shfl_xor(mx, 16));
    mx = fmaxf(mx, __shfl_xor(mx, 32));
    // defer-max: rescale only if some row's max grew
    if (__any(mx > mrun)) {
      float mnew = fmaxf(mrun, mx);
      float corr = exp2f(mrun - mnew);
      lrun *= corr;
      mrun = mnew;
      float c4[4];
      #pragma unroll
      for (int r = 0; r < 4; ++r) c4[r] = __shfl(corr, fq*4 + r, 16);
      #pragma unroll
      for (int db = 0; db < 4; ++db)
        #pragma unroll
        for (int r = 0; r < 4; ++r) o[db][r] *= c4[r];
    }
    // exponentiate (exp2, scores pre-scaled) + partial sum, then 2 shuffles
    float ts = 0.f;
    #pragma unroll
    for (int nb = 0; nb < 4; ++nb)
      #pragma unroll
      for (int r = 0; r < 4; ++r) {
        float p = exp2f(s[nb][r] - mrun);
        s[nb][r] = p;
        ts += p;
      }
    ts += __shfl_xor(ts, 16);
    ts += __shfl_xor(ts, 32);
    lrun += ts;
    // P write: 4 consecutive k per lane -> packed 8B writes, row = q-local = fr
    #pragma unroll
    for (int nb = 0; nb < 4; ++nb) {
      unsigned lo = cvtpk(s[nb][0], s[nb][1]);
      unsigned hi = cvtpk(s[nb][2], s[nb][3]);
      *(uint2*)(pw + fr * LDP + nb*16 + fq*4) = make_uint2(lo, hi);
    }
    // PV: A = P rows (q), B = Vt rows (d). In-order wave LDS -> no barrier.
    bf16x8 pa[2];
    #pragma unroll
    for (int j = 0; j < 2; ++j)
      pa[j] = *(const bf16x8*)(pw + fr * LDP + j*32 + fq*8);
    #pragma unroll
    for (int db = 0; db < 4; ++db) {
      o[db] = __builtin_amdgcn_mfma_f32_16x16x32_bf16(pa[0], bv[db][0], o[db], 0, 0, 0);
      o[db] = __builtin_amdgcn_mfma_f32_16x16x32_bf16(pa[1], bv[db][1], o[db], 0, 0, 0);
    }
  }
  // epilogue: lane's o rows are q = fq*4+r; fetch their denominators
  float l4[4];
  #pragma unroll
  for (int r = 0; r < 4; ++r) l4[r] = 1.0f / __shfl(lrun, fq*4 + r, 16);
  #pragma unroll
  for (int db = 0; db < 4; ++db)
    #pragma unroll
    for (int r = 0; r < 4; ++r) {
      int row = b * 2048 + q0 + fq*4 + r;
      int col = h * 64 + db*16 + fr;
      AO[(size_t)row * 512 + col] = o[db][r] * l4[r];
    }
}

extern "C" void kernel_launch(void* const* d_in, const int* in_sizes, int n_in,
                              void* d_out, int out_size, void* d_ws, size_t ws_size,
                              hipStream_t stream)
{
  const float* x     = (const float*)d_in[0];   // [4,2048,512] fp32
  const float* w_qkv = (const float*)d_in[1];   // [1536,512]  fp32
  const float* w_out = (const float*)d_in[2];   // [512,512]   fp32
  const float* temp  = (const float*)d_in[3];   // [8,1,1]     fp32
  float* out = (float*)d_out;                   // [4,2048,512] fp32
  short* ws  = (short*)d_ws;

  const size_t NQ = (size_t)4 * 8 * 2048 * 64;  // 4194304 elems per tensor
  short* Qb  = ws;                    // bf16 [b,h,n,64] normalized q * temp*log2e
  short* Kb  = ws + NQ;               // bf16 [b,h,n,64] normalized k
  short* Vtb = ws + 2 * NQ;           // bf16 [b,h,64,n]
  float* AOb = (float*)(ws + 3 * NQ); // fp32 [8192,512] attention output

  gemm_bt<1><<<dim3(12, 64), 256, 0, stream>>>(x, w_qkv, Qb, Kb, Vtb, nullptr, temp,
                                               8192, 1536, 512);
  // grid: x = bh (pins each head's K/V to one XCD L2), y = q-tile
  attn_fwd<<<dim3(32, 32), 256, 0, stream>>>(Qb, Kb, Vtb, AOb);
  gemm_bt<0><<<dim3(4, 64), 256, 0, stream>>>(AOb, w_out, nullptr, nullptr, nullptr, out,
                                              nullptr, 8192, 512, 512);
}

// Round 5
// 148.963 us; speedup vs baseline: 2.0297x; 2.0297x over previous
//
#include <hip/hip_runtime.h>
#include <hip/hip_bf16.h>

using bf16x8 = __attribute__((ext_vector_type(8))) short;
using f32x4  = __attribute__((ext_vector_type(4))) float;

__device__ __forceinline__ short f2bf(float f) {
  union { float f; unsigned u; } v; v.f = f;
  unsigned r = (v.u + 0x7FFFu + ((v.u >> 16) & 1u)) >> 16;
  return (short)(unsigned short)r;
}

__device__ __forceinline__ unsigned cvtpk(float lo, float hi) {
  unsigned r;
  asm("v_cvt_pk_bf16_f32 %0, %1, %2" : "=v"(r) : "v"(lo), "v"(hi));
  return r;
}

__device__ __forceinline__ bf16x8 ld8f(const float* __restrict__ p) {
  float4 lo = *(const float4*)p;
  float4 hi = *(const float4*)(p + 4);
  bf16x8 r;
  r[0] = f2bf(lo.x); r[1] = f2bf(lo.y); r[2] = f2bf(lo.z); r[3] = f2bf(lo.w);
  r[4] = f2bf(hi.x); r[5] = f2bf(hi.y); r[6] = f2bf(hi.z); r[7] = f2bf(hi.w);
  return r;
}

#define BM 128
#define BN 128
#define BKSTEP 32
#define LDK 40

template<int MODE>
__global__ __launch_bounds__(256, 2)
void gemm_bt(const float* __restrict__ A, const float* __restrict__ B,
             short* __restrict__ outQ, short* __restrict__ outK, short* __restrict__ outVt,
             float* __restrict__ outC,
             const float* __restrict__ temp,
             int M, int N, int Kd)
{
  __shared__ short As[BM * LDK];
  __shared__ short Bs[BN * LDK];
  const int tid  = threadIdx.x;
  const int lane = tid & 63;
  const int w    = tid >> 6;
  const int wr   = w >> 1, wc = w & 1;
  const int fr   = lane & 15, fq = lane >> 4;
  const int bm = blockIdx.y, bn = blockIdx.x;
  const int rowA = bm * BM, rowB = bn * BN;
  const int sr = tid >> 2;
  const int sc = (tid & 3) * 8;

  f32x4 acc[4][4];
  #pragma unroll
  for (int m = 0; m < 4; ++m)
    #pragma unroll
    for (int n = 0; n < 4; ++n) acc[m][n] = (f32x4){0.f, 0.f, 0.f, 0.f};

  for (int k0 = 0; k0 < Kd; k0 += BKSTEP) {
    bf16x8 a0 = ld8f(A + (size_t)(rowA + sr)      * Kd + k0 + sc);
    bf16x8 a1 = ld8f(A + (size_t)(rowA + 64 + sr) * Kd + k0 + sc);
    bf16x8 b0 = ld8f(B + (size_t)(rowB + sr)      * Kd + k0 + sc);
    bf16x8 b1 = ld8f(B + (size_t)(rowB + 64 + sr) * Kd + k0 + sc);
    __syncthreads();
    *(bf16x8*)(As + sr * LDK + sc)        = a0;
    *(bf16x8*)(As + (64 + sr) * LDK + sc) = a1;
    *(bf16x8*)(Bs + sr * LDK + sc)        = b0;
    *(bf16x8*)(Bs + (64 + sr) * LDK + sc) = b1;
    __syncthreads();
    bf16x8 afr[4], bfr[4];
    #pragma unroll
    for (int m = 0; m < 4; ++m)
      afr[m] = *(const bf16x8*)(As + (wr*64 + m*16 + fr) * LDK + fq*8);
    #pragma unroll
    for (int n = 0; n < 4; ++n)
      bfr[n] = *(const bf16x8*)(Bs + (wc*64 + n*16 + fr) * LDK + fq*8);
    #pragma unroll
    for (int m = 0; m < 4; ++m)
      #pragma unroll
      for (int n = 0; n < 4; ++n)
        acc[m][n] = __builtin_amdgcn_mfma_f32_16x16x32_bf16(afr[m], bfr[n], acc[m][n], 0, 0, 0);
  }

  if (MODE == 0) {
    #pragma unroll
    for (int m = 0; m < 4; ++m) {
      int r0 = rowA + wr*64 + m*16 + fq*4;
      #pragma unroll
      for (int n = 0; n < 4; ++n) {
        int c = rowB + wc*64 + n*16 + fr;
        #pragma unroll
        for (int r = 0; r < 4; ++r)
          outC[(size_t)(r0 + r) * N + c] = acc[m][n][r];
      }
    }
  } else {
    const int gc0   = rowB + wc*64;
    const int slice = gc0 >> 6;
    const int t3    = slice >> 3;
    const int h     = slice & 7;
    if (t3 < 2) {
      float scl[4][4];
      const float tval = (t3 == 0) ? temp[h] * 1.44269504088896f : 1.0f;
      #pragma unroll
      for (int m = 0; m < 4; ++m) {
        #pragma unroll
        for (int r = 0; r < 4; ++r) {
          float ss = 0.f;
          #pragma unroll
          for (int n = 0; n < 4; ++n) ss += acc[m][n][r] * acc[m][n][r];
          #pragma unroll
          for (int off = 1; off < 16; off <<= 1) ss += __shfl_xor(ss, off);
          scl[m][r] = tval / fmaxf(sqrtf(ss), 1e-12f);
        }
      }
      short* dst = (t3 == 0) ? outQ : outK;
      #pragma unroll
      for (int m = 0; m < 4; ++m) {
        #pragma unroll
        for (int r = 0; r < 4; ++r) {
          int rg = rowA + wr*64 + m*16 + fq*4 + r;
          int b = rg >> 11, nn = rg & 2047;
          size_t rowoff = ((size_t)(b*8 + h) * 2048 + nn) * 64;
          #pragma unroll
          for (int n = 0; n < 4; ++n)
            dst[rowoff + n*16 + fr] = f2bf(acc[m][n][r] * scl[m][r]);
        }
      }
    } else {
      #pragma unroll
      for (int m = 0; m < 4; ++m) {
        #pragma unroll
        for (int r = 0; r < 4; ++r) {
          int rg = rowA + wr*64 + m*16 + fq*4 + r;
          int b = rg >> 11, nn = rg & 2047;
          #pragma unroll
          for (int n = 0; n < 4; ++n)
            outVt[((size_t)(b*8 + h) * 64 + n*16 + fr) * 2048 + nn] = f2bf(acc[m][n][r]);
        }
      }
    }
  }
}

// Flash attention, swapped-QK^T, cooperative double-buffered LDS staging of
// K/V tiles (XOR-swizzled, 2-way max bank aliasing), per-wave P buffer.
// LDS = 2*8K (K) + 2*8K (V) + 8K (P) = 40KB -> 4 blocks/CU.
__global__ __launch_bounds__(256, 4)
void attn_fwd(const short* __restrict__ Q, const short* __restrict__ Kt,
              const short* __restrict__ Vt, float* __restrict__ AO)
{
  __shared__ short Kl[2][64 * 64];
  __shared__ short Vl[2][64 * 64];
  __shared__ short Pl[4][16 * 64];
  const int tid  = threadIdx.x;
  const int lane = tid & 63;
  const int w    = tid >> 6;
  const int fr   = lane & 15, fq = lane >> 4;
  const int bh = blockIdx.x;          // XCD = bh%8: 4 heads' K/V per XCD L2
  const int qt = blockIdx.y;
  const int b = bh >> 3, h = bh & 7;
  const size_t base  = (size_t)bh * 2048 * 64;
  const size_t vbase = (size_t)bh * 64 * 2048;
  const int q0 = qt * 64 + w * 16;

  const short* kp = Kt + base;
  const short* vp = Vt + vbase;

  // staging: thread -> row tid>>2 (of 64), chunks (tid&3)*16 + j*64 bytes
  const int srow = tid >> 2;
  const int scol = (tid & 3) * 16;            // byte
  const int sxor = (srow & 7) << 4;
  const int fxor = (fr & 7) << 4;

  bf16x8 stK[2], stV[2];
  #define LOAD_TILE(T)                                                          \
    do { int kt_ = (T) * 64;                                                    \
      stK[0] = *(const bf16x8*)(kp + (size_t)(kt_ + srow) * 64 + (scol >> 1));  \
      stK[1] = *(const bf16x8*)(kp + (size_t)(kt_ + srow) * 64 + (scol >> 1) + 32); \
      stV[0] = *(const bf16x8*)(vp + (size_t)srow * 2048 + kt_ + (scol >> 1));  \
      stV[1] = *(const bf16x8*)(vp + (size_t)srow * 2048 + kt_ + (scol >> 1) + 32); \
    } while (0)
  #define WRITE_TILE(P_)                                                        \
    do {                                                                        \
      *(bf16x8*)((char*)Kl[P_] + srow * 128 + ((scol)      ^ sxor)) = stK[0];   \
      *(bf16x8*)((char*)Kl[P_] + srow * 128 + ((scol + 64) ^ sxor)) = stK[1];   \
      *(bf16x8*)((char*)Vl[P_] + srow * 128 + ((scol)      ^ sxor)) = stV[0];   \
      *(bf16x8*)((char*)Vl[P_] + srow * 128 + ((scol + 64) ^ sxor)) = stV[1];   \
    } while (0)

  // Q fragment (B-operand): lane holds Q row q0+fr, d-elems fq*8..+7 (+32)
  bf16x8 bq[2];
  #pragma unroll
  for (int j = 0; j < 2; ++j)
    bq[j] = *(const bf16x8*)(Q + base + (size_t)(q0 + fr) * 64 + j*32 + fq*8);

  f32x4 o[4];
  #pragma unroll
  for (int db = 0; db < 4; ++db) o[db] = (f32x4){0.f, 0.f, 0.f, 0.f};
  float mrun = -1e30f;
  float lrun = 0.f;

  char* pw = (char*)&Pl[w][0];

  // prologue: tile 0 -> buf0; tile 1 -> regs
  LOAD_TILE(0);
  WRITE_TILE(0);
  LOAD_TILE(1);
  __syncthreads();

  for (int t = 0; t < 32; ++t) {
    const int p = t & 1;
    const char* kl = (const char*)Kl[p];
    const char* vl = (const char*)Vl[p];

    // S^T: A = K rows (k), B = Q rows (q); lane: s[nb][r] = S[q0+fr][nb*16+fq*4+r]
    f32x4 s[4];
    #pragma unroll
    for (int nb = 0; nb < 4; ++nb) {
      bf16x8 ak0 = *(const bf16x8*)(kl + (nb*16 + fr) * 128 + ((      fq*16) ^ fxor));
      bf16x8 ak1 = *(const bf16x8*)(kl + (nb*16 + fr) * 128 + ((64 + fq*16) ^ fxor));
      f32x4 z = (f32x4){0.f, 0.f, 0.f, 0.f};
      z = __builtin_amdgcn_mfma_f32_16x16x32_bf16(ak0, bq[0], z, 0, 0, 0);
      z = __builtin_amdgcn_mfma_f32_16x16x32_bf16(ak1, bq[1], z, 0, 0, 0);
      s[nb] = z;
    }
    // softmax (log2-domain, temp*log2e pre-folded into Q)
    float mx = s[0][0];
    #pragma unroll
    for (int nb = 0; nb < 4; ++nb)
      #pragma unroll
      for (int r = 0; r < 4; ++r) mx = fmaxf(mx, s[nb][r]);
    mx = fmaxf(mx, __shfl_xor(mx, 16));
    mx = fmaxf(mx, __shfl_xor(mx, 32));
    if (__any(mx > mrun)) {
      float mnew = fmaxf(mrun, mx);
      float corr = exp2f(mrun - mnew);
      lrun *= corr;
      mrun = mnew;
      float c4[4];
      #pragma unroll
      for (int r = 0; r < 4; ++r) c4[r] = __shfl(corr, fq*4 + r, 16);
      #pragma unroll
      for (int db = 0; db < 4; ++db)
        #pragma unroll
        for (int r = 0; r < 4; ++r) o[db][r] *= c4[r];
    }
    float ts = 0.f;
    #pragma unroll
    for (int nb = 0; nb < 4; ++nb)
      #pragma unroll
      for (int r = 0; r < 4; ++r) {
        float pv = exp2f(s[nb][r] - mrun);
        s[nb][r] = pv;
        ts += pv;
      }
    ts += __shfl_xor(ts, 16);
    ts += __shfl_xor(ts, 32);
    lrun += ts;
    // P write (swizzled, per-wave, no barrier needed)
    #pragma unroll
    for (int nb = 0; nb < 4; ++nb) {
      unsigned lo = cvtpk(s[nb][0], s[nb][1]);
      unsigned hi = cvtpk(s[nb][2], s[nb][3]);
      *(uint2*)(pw + fr * 128 + ((nb*32 + fq*8) ^ fxor)) = make_uint2(lo, hi);
    }
    bf16x8 pa[2];
    #pragma unroll
    for (int j = 0; j < 2; ++j)
      pa[j] = *(const bf16x8*)(pw + fr * 128 + ((j*64 + fq*16) ^ fxor));
    // PV: A = P rows (q), B = V rows (d)
    #pragma unroll
    for (int db = 0; db < 4; ++db) {
      bf16x8 bv0 = *(const bf16x8*)(vl + (db*16 + fr) * 128 + ((      fq*16) ^ fxor));
      bf16x8 bv1 = *(const bf16x8*)(vl + (db*16 + fr) * 128 + ((64 + fq*16) ^ fxor));
      o[db] = __builtin_amdgcn_mfma_f32_16x16x32_bf16(pa[0], bv0, o[db], 0, 0, 0);
      o[db] = __builtin_amdgcn_mfma_f32_16x16x32_bf16(pa[1], bv1, o[db], 0, 0, 0);
    }

    __syncthreads();               // A: all waves done reading buf p
    if (t < 31) {
      WRITE_TILE(p ^ 1);           // tile t+1 (regs) -> other buffer
      if (t < 30) LOAD_TILE(t + 2);
      __syncthreads();             // B: buffer ready for next iter
    }
  }
  #undef LOAD_TILE
  #undef WRITE_TILE

  float l4[4];
  #pragma unroll
  for (int r = 0; r < 4; ++r) l4[r] = 1.0f / __shfl(lrun, fq*4 + r, 16);
  #pragma unroll
  for (int db = 0; db < 4; ++db)
    #pragma unroll
    for (int r = 0; r < 4; ++r) {
      int row = b * 2048 + q0 + fq*4 + r;
      int col = h * 64 + db*16 + fr;
      AO[(size_t)row * 512 + col] = o[db][r] * l4[r];
    }
}

extern "C" void kernel_launch(void* const* d_in, const int* in_sizes, int n_in,
                              void* d_out, int out_size, void* d_ws, size_t ws_size,
                              hipStream_t stream)
{
  const float* x     = (const float*)d_in[0];
  const float* w_qkv = (const float*)d_in[1];
  const float* w_out = (const float*)d_in[2];
  const float* temp  = (const float*)d_in[3];
  float* out = (float*)d_out;
  short* ws  = (short*)d_ws;

  const size_t NQ = (size_t)4 * 8 * 2048 * 64;
  short* Qb  = ws;
  short* Kb  = ws + NQ;
  short* Vtb = ws + 2 * NQ;
  float* AOb = (float*)(ws + 3 * NQ);

  gemm_bt<1><<<dim3(12, 64), 256, 0, stream>>>(x, w_qkv, Qb, Kb, Vtb, nullptr, temp,
                                               8192, 1536, 512);
  attn_fwd<<<dim3(32, 32), 256, 0, stream>>>(Qb, Kb, Vtb, AOb);
  gemm_bt<0><<<dim3(4, 64), 256, 0, stream>>>(AOb, w_out, nullptr, nullptr, nullptr, out,
                                              nullptr, 8192, 512, 512);
}

// Round 6
// 135.196 us; speedup vs baseline: 2.2364x; 1.1018x over previous
//
#include <hip/hip_runtime.h>
#include <hip/hip_bf16.h>

using bf16x8 = __attribute__((ext_vector_type(8))) short;
using f32x4  = __attribute__((ext_vector_type(4))) float;

__device__ __forceinline__ short f2bf(float f) {
  union { float f; unsigned u; } v; v.f = f;
  unsigned r = (v.u + 0x7FFFu + ((v.u >> 16) & 1u)) >> 16;
  return (short)(unsigned short)r;
}

__device__ __forceinline__ unsigned cvtpk(float lo, float hi) {
  unsigned r;
  asm("v_cvt_pk_bf16_f32 %0, %1, %2" : "=v"(r) : "v"(lo), "v"(hi));
  return r;
}

__device__ __forceinline__ bf16x8 ld8f(const float* __restrict__ p) {
  float4 lo = *(const float4*)p;
  float4 hi = *(const float4*)(p + 4);
  bf16x8 r;
  r[0] = f2bf(lo.x); r[1] = f2bf(lo.y); r[2] = f2bf(lo.z); r[3] = f2bf(lo.w);
  r[4] = f2bf(hi.x); r[5] = f2bf(hi.y); r[6] = f2bf(hi.z); r[7] = f2bf(hi.w);
  return r;
}

#define BM 128
#define BN 128
#define BKSTEP 32
#define LDK 40

template<int MODE>
__global__ __launch_bounds__(256, 2)
void gemm_bt(const float* __restrict__ A, const float* __restrict__ B,
             short* __restrict__ outQ, short* __restrict__ outK, short* __restrict__ outVt,
             float* __restrict__ outC,
             const float* __restrict__ temp,
             int M, int N, int Kd)
{
  __shared__ short As[BM * LDK];
  __shared__ short Bs[BN * LDK];
  const int tid  = threadIdx.x;
  const int lane = tid & 63;
  const int w    = tid >> 6;
  const int wr   = w >> 1, wc = w & 1;
  const int fr   = lane & 15, fq = lane >> 4;
  const int bm = blockIdx.y, bn = blockIdx.x;
  const int rowA = bm * BM, rowB = bn * BN;
  const int sr = tid >> 2;
  const int sc = (tid & 3) * 8;

  f32x4 acc[4][4];
  #pragma unroll
  for (int m = 0; m < 4; ++m)
    #pragma unroll
    for (int n = 0; n < 4; ++n) acc[m][n] = (f32x4){0.f, 0.f, 0.f, 0.f};

  for (int k0 = 0; k0 < Kd; k0 += BKSTEP) {
    bf16x8 a0 = ld8f(A + (size_t)(rowA + sr)      * Kd + k0 + sc);
    bf16x8 a1 = ld8f(A + (size_t)(rowA + 64 + sr) * Kd + k0 + sc);
    bf16x8 b0 = ld8f(B + (size_t)(rowB + sr)      * Kd + k0 + sc);
    bf16x8 b1 = ld8f(B + (size_t)(rowB + 64 + sr) * Kd + k0 + sc);
    __syncthreads();
    *(bf16x8*)(As + sr * LDK + sc)        = a0;
    *(bf16x8*)(As + (64 + sr) * LDK + sc) = a1;
    *(bf16x8*)(Bs + sr * LDK + sc)        = b0;
    *(bf16x8*)(Bs + (64 + sr) * LDK + sc) = b1;
    __syncthreads();
    bf16x8 afr[4], bfr[4];
    #pragma unroll
    for (int m = 0; m < 4; ++m)
      afr[m] = *(const bf16x8*)(As + (wr*64 + m*16 + fr) * LDK + fq*8);
    #pragma unroll
    for (int n = 0; n < 4; ++n)
      bfr[n] = *(const bf16x8*)(Bs + (wc*64 + n*16 + fr) * LDK + fq*8);
    #pragma unroll
    for (int m = 0; m < 4; ++m)
      #pragma unroll
      for (int n = 0; n < 4; ++n)
        acc[m][n] = __builtin_amdgcn_mfma_f32_16x16x32_bf16(afr[m], bfr[n], acc[m][n], 0, 0, 0);
  }

  if (MODE == 0) {
    #pragma unroll
    for (int m = 0; m < 4; ++m) {
      int r0 = rowA + wr*64 + m*16 + fq*4;
      #pragma unroll
      for (int n = 0; n < 4; ++n) {
        int c = rowB + wc*64 + n*16 + fr;
        #pragma unroll
        for (int r = 0; r < 4; ++r)
          outC[(size_t)(r0 + r) * N + c] = acc[m][n][r];
      }
    }
  } else {
    const int gc0   = rowB + wc*64;
    const int slice = gc0 >> 6;
    const int t3    = slice >> 3;
    const int h     = slice & 7;
    if (t3 < 2) {
      float scl[4][4];
      const float tval = (t3 == 0) ? temp[h] * 1.44269504088896f : 1.0f;
      #pragma unroll
      for (int m = 0; m < 4; ++m) {
        #pragma unroll
        for (int r = 0; r < 4; ++r) {
          float ss = 0.f;
          #pragma unroll
          for (int n = 0; n < 4; ++n) ss += acc[m][n][r] * acc[m][n][r];
          #pragma unroll
          for (int off = 1; off < 16; off <<= 1) ss += __shfl_xor(ss, off);
          scl[m][r] = tval / fmaxf(sqrtf(ss), 1e-12f);
        }
      }
      short* dst = (t3 == 0) ? outQ : outK;
      #pragma unroll
      for (int m = 0; m < 4; ++m) {
        #pragma unroll
        for (int r = 0; r < 4; ++r) {
          int rg = rowA + wr*64 + m*16 + fq*4 + r;
          int b = rg >> 11, nn = rg & 2047;
          size_t rowoff = ((size_t)(b*8 + h) * 2048 + nn) * 64;
          #pragma unroll
          for (int n = 0; n < 4; ++n)
            dst[rowoff + n*16 + fr] = f2bf(acc[m][n][r] * scl[m][r]);
        }
      }
    } else {
      #pragma unroll
      for (int m = 0; m < 4; ++m) {
        #pragma unroll
        for (int r = 0; r < 4; ++r) {
          int rg = rowA + wr*64 + m*16 + fq*4 + r;
          int b = rg >> 11, nn = rg & 2047;
          #pragma unroll
          for (int n = 0; n < 4; ++n)
            outVt[((size_t)(b*8 + h) * 64 + n*16 + fr) * 2048 + nn] = f2bf(acc[m][n][r]);
        }
      }
    }
  }
}

// Flash attention for COSINE attention: scores bounded by M_h = |temp|*log2e
// (Cauchy-Schwarz), so softmax uses a STATIC max — no online rescale at all.
// s - M comes free via the MFMA C-operand. Swapped-QK^T layout; cooperative
// double-buffered LDS staging (XOR-swizzled, conflict-free); per-wave P buf.
// LDS = 40KB -> 4 blocks/CU.
__global__ __launch_bounds__(256, 4)
void attn_fwd(const short* __restrict__ Q, const short* __restrict__ Kt,
              const short* __restrict__ Vt, float* __restrict__ AO,
              const float* __restrict__ temp)
{
  __shared__ short Kl[2][64 * 64];
  __shared__ short Vl[2][64 * 64];
  __shared__ short Pl[4][16 * 64];
  const int tid  = threadIdx.x;
  const int lane = tid & 63;
  const int w    = tid >> 6;
  const int fr   = lane & 15, fq = lane >> 4;
  const int bh = blockIdx.x;          // XCD = bh%8: 4 heads' K/V per XCD L2
  const int qt = blockIdx.y;
  const int b = bh >> 3, h = bh & 7;
  const size_t base  = (size_t)bh * 2048 * 64;
  const size_t vbase = (size_t)bh * 64 * 2048;
  const int q0 = qt * 64 + w * 16;

  const short* kp = Kt + base;
  const short* vp = Vt + vbase;

  // staging: thread -> row tid>>3 (+j*32), 16B chunk tid&7 within the 128B row
  const int srow  = tid >> 3;           // 0..31
  const int scol8 = (tid & 7) * 8;      // elem offset (16B chunk)
  const int scolB = (tid & 7) * 16;     // byte offset
  const int sxor  = (srow & 7) << 4;    // (j*32+srow)&7 == srow&7
  const int fxor  = (fr & 7) << 4;

  bf16x8 stK[2], stV[2];
  #define LOAD_TILE(T)                                                              \
    do { int kt_ = (T) * 64;                                                        \
      stK[0] = *(const bf16x8*)(kp + (size_t)(kt_ + srow)      * 64 + scol8);       \
      stK[1] = *(const bf16x8*)(kp + (size_t)(kt_ + 32 + srow) * 64 + scol8);       \
      stV[0] = *(const bf16x8*)(vp + (size_t)srow        * 2048 + kt_ + scol8);     \
      stV[1] = *(const bf16x8*)(vp + (size_t)(32 + srow) * 2048 + kt_ + scol8);     \
    } while (0)
  #define WRITE_TILE(P_)                                                            \
    do {                                                                            \
      *(bf16x8*)((char*)Kl[P_] + (srow)      * 128 + (scolB ^ sxor)) = stK[0];      \
      *(bf16x8*)((char*)Kl[P_] + (32 + srow) * 128 + (scolB ^ sxor)) = stK[1];      \
      *(bf16x8*)((char*)Vl[P_] + (srow)      * 128 + (scolB ^ sxor)) = stV[0];      \
      *(bf16x8*)((char*)Vl[P_] + (32 + srow) * 128 + (scolB ^ sxor)) = stV[1];      \
    } while (0)

  // Q fragment (B-operand): lane holds Q row q0+fr, d-elems fq*8..+7 (+32)
  bf16x8 bq[2];
  #pragma unroll
  for (int j = 0; j < 2; ++j)
    bq[j] = *(const bf16x8*)(Q + base + (size_t)(q0 + fr) * 64 + j*32 + fq*8);

  // static softmax max: |q̂·k̂| <= 1  =>  s <= |temp|*log2e  (exact bound)
  const float Mh = fabsf(temp[h]) * 1.44269504088896f;
  const f32x4 cinit = (f32x4){-Mh, -Mh, -Mh, -Mh};

  f32x4 o[4];
  #pragma unroll
  for (int db = 0; db < 4; ++db) o[db] = (f32x4){0.f, 0.f, 0.f, 0.f};
  float lp = 0.f;   // per-lane partial sum of P (reduced once at the end)

  char* pw = (char*)&Pl[w][0];

  LOAD_TILE(0);
  WRITE_TILE(0);
  LOAD_TILE(1);
  __syncthreads();

  for (int t = 0; t < 32; ++t) {
    const int p = t & 1;
    const char* kl = (const char*)Kl[p];
    const char* vl = (const char*)Vl[p];

    // S^T - M: A = K rows (k), B = Q rows (q), C = -M.
    // lane: s[nb][r] = S[q0+fr][nb*16+fq*4+r] - Mh   (log2 units)
    f32x4 s[4];
    #pragma unroll
    for (int nb = 0; nb < 4; ++nb) {
      bf16x8 ak0 = *(const bf16x8*)(kl + (nb*16 + fr) * 128 + ((     fq*16) ^ fxor));
      bf16x8 ak1 = *(const bf16x8*)(kl + (nb*16 + fr) * 128 + ((64 + fq*16) ^ fxor));
      f32x4 z = cinit;
      z = __builtin_amdgcn_mfma_f32_16x16x32_bf16(ak0, bq[0], z, 0, 0, 0);
      z = __builtin_amdgcn_mfma_f32_16x16x32_bf16(ak1, bq[1], z, 0, 0, 0);
      s[nb] = z;
    }
    // P = exp2(s - M); accumulate per-lane partial denom
    #pragma unroll
    for (int nb = 0; nb < 4; ++nb)
      #pragma unroll
      for (int r = 0; r < 4; ++r) {
        float pv = exp2f(s[nb][r]);
        s[nb][r] = pv;
        lp += pv;
      }
    // P write (swizzled, per-wave, no barrier needed)
    #pragma unroll
    for (int nb = 0; nb < 4; ++nb) {
      unsigned lo = cvtpk(s[nb][0], s[nb][1]);
      unsigned hi = cvtpk(s[nb][2], s[nb][3]);
      *(uint2*)(pw + fr * 128 + ((nb*32 + fq*8) ^ fxor)) = make_uint2(lo, hi);
    }
    bf16x8 pa[2];
    #pragma unroll
    for (int j = 0; j < 2; ++j)
      pa[j] = *(const bf16x8*)(pw + fr * 128 + ((j*64 + fq*16) ^ fxor));
    // PV: A = P rows (q), B = V rows (d)
    #pragma unroll
    for (int db = 0; db < 4; ++db) {
      bf16x8 bv0 = *(const bf16x8*)(vl + (db*16 + fr) * 128 + ((     fq*16) ^ fxor));
      bf16x8 bv1 = *(const bf16x8*)(vl + (db*16 + fr) * 128 + ((64 + fq*16) ^ fxor));
      o[db] = __builtin_amdgcn_mfma_f32_16x16x32_bf16(pa[0], bv0, o[db], 0, 0, 0);
      o[db] = __builtin_amdgcn_mfma_f32_16x16x32_bf16(pa[1], bv1, o[db], 0, 0, 0);
    }

    __syncthreads();               // all waves done reading buf p
    if (t < 31) {
      WRITE_TILE(p ^ 1);
      if (t < 30) LOAD_TILE(t + 2);
      __syncthreads();
    }
  }
  #undef LOAD_TILE
  #undef WRITE_TILE

  // final denom: row q=fr lives in lanes {fr, fr+16, fr+32, fr+48}
  lp += __shfl_xor(lp, 16);
  lp += __shfl_xor(lp, 32);
  float l4[4];
  #pragma unroll
  for (int r = 0; r < 4; ++r) l4[r] = 1.0f / __shfl(lp, fq*4 + r, 16);
  #pragma unroll
  for (int db = 0; db < 4; ++db)
    #pragma unroll
    for (int r = 0; r < 4; ++r) {
      int row = b * 2048 + q0 + fq*4 + r;
      int col = h * 64 + db*16 + fr;
      AO[(size_t)row * 512 + col] = o[db][r] * l4[r];
    }
}

extern "C" void kernel_launch(void* const* d_in, const int* in_sizes, int n_in,
                              void* d_out, int out_size, void* d_ws, size_t ws_size,
                              hipStream_t stream)
{
  const float* x     = (const float*)d_in[0];
  const float* w_qkv = (const float*)d_in[1];
  const float* w_out = (const float*)d_in[2];
  const float* temp  = (const float*)d_in[3];
  float* out = (float*)d_out;
  short* ws  = (short*)d_ws;

  const size_t NQ = (size_t)4 * 8 * 2048 * 64;
  short* Qb  = ws;
  short* Kb  = ws + NQ;
  short* Vtb = ws + 2 * NQ;
  float* AOb = (float*)(ws + 3 * NQ);

  gemm_bt<1><<<dim3(12, 64), 256, 0, stream>>>(x, w_qkv, Qb, Kb, Vtb, nullptr, temp,
                                               8192, 1536, 512);
  attn_fwd<<<dim3(32, 32), 256, 0, stream>>>(Qb, Kb, Vtb, AOb, temp);
  gemm_bt<0><<<dim3(4, 64), 256, 0, stream>>>(AOb, w_out, nullptr, nullptr, nullptr, out,
                                              nullptr, 8192, 512, 512);
}

// Round 7
// 127.422 us; speedup vs baseline: 2.3729x; 1.0610x over previous
//
#include <hip/hip_runtime.h>
#include <hip/hip_bf16.h>

using bf16x8 = __attribute__((ext_vector_type(8))) short;
using f32x4  = __attribute__((ext_vector_type(4))) float;

__device__ __forceinline__ short f2bf(float f) {
  union { float f; unsigned u; } v; v.f = f;
  unsigned r = (v.u + 0x7FFFu + ((v.u >> 16) & 1u)) >> 16;
  return (short)(unsigned short)r;
}

__device__ __forceinline__ unsigned cvtpk(float lo, float hi) {
  unsigned r;
  asm("v_cvt_pk_bf16_f32 %0, %1, %2" : "=v"(r) : "v"(lo), "v"(hi));
  return r;
}

__device__ __forceinline__ bf16x8 ld8f(const float* __restrict__ p) {
  float4 lo = *(const float4*)p;
  float4 hi = *(const float4*)(p + 4);
  bf16x8 r;
  r[0] = f2bf(lo.x); r[1] = f2bf(lo.y); r[2] = f2bf(lo.z); r[3] = f2bf(lo.w);
  r[4] = f2bf(hi.x); r[5] = f2bf(hi.y); r[6] = f2bf(hi.z); r[7] = f2bf(hi.w);
  return r;
}

#define GLLDS(gp, lp) __builtin_amdgcn_global_load_lds(                        \
    (const __attribute__((address_space(1))) void*)(gp),                       \
    (__attribute__((address_space(3))) void*)(lp), 16, 0, 0)

// ---------------- fp32 -> bf16 conversion (vectorized, 8 elems/thread) -----
__global__ __launch_bounds__(256)
void cvt_f32_bf16(const float* __restrict__ in, short* __restrict__ out, int n8)
{
  int i = blockIdx.x * 256 + threadIdx.x;
  if (i >= n8) return;
  float4 lo = *(const float4*)(in + (size_t)i * 8);
  float4 hi = *(const float4*)(in + (size_t)i * 8 + 4);
  uint4 r;
  r.x = cvtpk(lo.x, lo.y);
  r.y = cvtpk(lo.z, lo.w);
  r.z = cvtpk(hi.x, hi.y);
  r.w = cvtpk(hi.z, hi.w);
  *(uint4*)(out + (size_t)i * 8) = r;
}

// ---------------- QKV projection: bf16 GEMM, global_load_lds staging -------
// C = A[8192,512] * B[1536,512]^T, 128x128 tile, BK=32, m97 2-barrier loop.
// LDS layout: row r (64B) holds 4 16B-chunks; chunk slot c' = c ^ ((r>>1)&3).
// Staging writes linearly (lds-direct); per-lane GLOBAL addr pre-swizzled.
// Epilogue: l2norm q,k rows, temp*log2e into q; scatter Q,K,[b,h,n,d], Vt[b,h,d,n].
__global__ __launch_bounds__(256, 2)
void gemm_qkv(const short* __restrict__ A, const short* __restrict__ B,
              short* __restrict__ outQ, short* __restrict__ outK,
              short* __restrict__ outVt, const float* __restrict__ temp)
{
  __shared__ short As[128 * 32];
  __shared__ short Bs[128 * 32];
  const int Kd = 512;
  const int tid  = threadIdx.x;
  const int lane = tid & 63;
  const int w    = tid >> 6;
  const int wr   = w >> 1, wc = w & 1;
  const int fr   = lane & 15, fq = lane >> 4;
  const int bm = blockIdx.y, bn = blockIdx.x;
  const int rowA = bm * 128, rowB = bn * 128;

  // staging geometry: instr covers 16 rows; lane -> row +(lane>>2), slot lane&3
  const int lrow   = lane >> 2;
  const int lchunk = ((lane & 3) ^ ((lane >> 3) & 3)) * 8;  // global chunk (elems)
  const short* gA0 = A + (size_t)(rowA + w * 32 + lrow) * Kd + lchunk;
  const short* gB0 = B + (size_t)(rowB + w * 32 + lrow) * Kd + lchunk;
  char* lA0 = (char*)As + (w * 32) * 64;
  char* lB0 = (char*)Bs + (w * 32) * 64;

  // frag-read swizzle: chunk' = fq ^ ((fr>>1)&3)
  const int rxor = ((fr >> 1) & 3) << 4;

  f32x4 acc[4][4];
  #pragma unroll
  for (int m = 0; m < 4; ++m)
    #pragma unroll
    for (int n = 0; n < 4; ++n) acc[m][n] = (f32x4){0.f, 0.f, 0.f, 0.f};

  for (int k0 = 0; k0 < Kd; k0 += 32) {
    GLLDS(gA0 + k0,            lA0);
    GLLDS(gA0 + k0 + 16 * Kd,  lA0 + 1024);
    GLLDS(gB0 + k0,            lB0);
    GLLDS(gB0 + k0 + 16 * Kd,  lB0 + 1024);
    __syncthreads();   // drains vmcnt, then barrier: tiles visible
    bf16x8 afr[4], bfr[4];
    #pragma unroll
    for (int m = 0; m < 4; ++m)
      afr[m] = *(const bf16x8*)((char*)As + (wr*64 + m*16 + fr) * 64 + ((fq*16) ^ rxor));
    #pragma unroll
    for (int n = 0; n < 4; ++n)
      bfr[n] = *(const bf16x8*)((char*)Bs + (wc*64 + n*16 + fr) * 64 + ((fq*16) ^ rxor));
    #pragma unroll
    for (int m = 0; m < 4; ++m)
      #pragma unroll
      for (int n = 0; n < 4; ++n)
        acc[m][n] = __builtin_amdgcn_mfma_f32_16x16x32_bf16(afr[m], bfr[n], acc[m][n], 0, 0, 0);
    __syncthreads();   // WAR: frag reads done before next stage overwrites
  }

  // epilogue (unchanged from proven version)
  const int gc0   = rowB + wc*64;
  const int slice = gc0 >> 6;
  const int t3    = slice >> 3;
  const int h     = slice & 7;
  if (t3 < 2) {
    float scl[4][4];
    const float tval = (t3 == 0) ? temp[h] * 1.44269504088896f : 1.0f;
    #pragma unroll
    for (int m = 0; m < 4; ++m) {
      #pragma unroll
      for (int r = 0; r < 4; ++r) {
        float ss = 0.f;
        #pragma unroll
        for (int n = 0; n < 4; ++n) ss += acc[m][n][r] * acc[m][n][r];
        #pragma unroll
        for (int off = 1; off < 16; off <<= 1) ss += __shfl_xor(ss, off);
        scl[m][r] = tval / fmaxf(sqrtf(ss), 1e-12f);
      }
    }
    short* dst = (t3 == 0) ? outQ : outK;
    #pragma unroll
    for (int m = 0; m < 4; ++m) {
      #pragma unroll
      for (int r = 0; r < 4; ++r) {
        int rg = rowA + wr*64 + m*16 + fq*4 + r;
        int b = rg >> 11, nn = rg & 2047;
        size_t rowoff = ((size_t)(b*8 + h) * 2048 + nn) * 64;
        #pragma unroll
        for (int n = 0; n < 4; ++n)
          dst[rowoff + n*16 + fr] = f2bf(acc[m][n][r] * scl[m][r]);
      }
    }
  } else {
    #pragma unroll
    for (int m = 0; m < 4; ++m) {
      #pragma unroll
      for (int r = 0; r < 4; ++r) {
        int rg = rowA + wr*64 + m*16 + fq*4 + r;
        int b = rg >> 11, nn = rg & 2047;
        #pragma unroll
        for (int n = 0; n < 4; ++n)
          outVt[((size_t)(b*8 + h) * 64 + n*16 + fr) * 2048 + nn] = f2bf(acc[m][n][r]);
      }
    }
  }
}

// ---------------- output projection: fp32-staged GEMM (unchanged) ----------
#define BM 128
#define BN 128
#define LDK 40

__global__ __launch_bounds__(256, 2)
void gemm_out(const float* __restrict__ A, const float* __restrict__ B,
              float* __restrict__ outC, int M, int N, int Kd)
{
  __shared__ short As[BM * LDK];
  __shared__ short Bs[BN * LDK];
  const int tid  = threadIdx.x;
  const int lane = tid & 63;
  const int w    = tid >> 6;
  const int wr   = w >> 1, wc = w & 1;
  const int fr   = lane & 15, fq = lane >> 4;
  const int bm = blockIdx.y, bn = blockIdx.x;
  const int rowA = bm * BM, rowB = bn * BN;
  const int sr = tid >> 2;
  const int sc = (tid & 3) * 8;

  f32x4 acc[4][4];
  #pragma unroll
  for (int m = 0; m < 4; ++m)
    #pragma unroll
    for (int n = 0; n < 4; ++n) acc[m][n] = (f32x4){0.f, 0.f, 0.f, 0.f};

  for (int k0 = 0; k0 < Kd; k0 += 32) {
    bf16x8 a0 = ld8f(A + (size_t)(rowA + sr)      * Kd + k0 + sc);
    bf16x8 a1 = ld8f(A + (size_t)(rowA + 64 + sr) * Kd + k0 + sc);
    bf16x8 b0 = ld8f(B + (size_t)(rowB + sr)      * Kd + k0 + sc);
    bf16x8 b1 = ld8f(B + (size_t)(rowB + 64 + sr) * Kd + k0 + sc);
    __syncthreads();
    *(bf16x8*)(As + sr * LDK + sc)        = a0;
    *(bf16x8*)(As + (64 + sr) * LDK + sc) = a1;
    *(bf16x8*)(Bs + sr * LDK + sc)        = b0;
    *(bf16x8*)(Bs + (64 + sr) * LDK + sc) = b1;
    __syncthreads();
    bf16x8 afr[4], bfr[4];
    #pragma unroll
    for (int m = 0; m < 4; ++m)
      afr[m] = *(const bf16x8*)(As + (wr*64 + m*16 + fr) * LDK + fq*8);
    #pragma unroll
    for (int n = 0; n < 4; ++n)
      bfr[n] = *(const bf16x8*)(Bs + (wc*64 + n*16 + fr) * LDK + fq*8);
    #pragma unroll
    for (int m = 0; m < 4; ++m)
      #pragma unroll
      for (int n = 0; n < 4; ++n)
        acc[m][n] = __builtin_amdgcn_mfma_f32_16x16x32_bf16(afr[m], bfr[n], acc[m][n], 0, 0, 0);
  }

  #pragma unroll
  for (int m = 0; m < 4; ++m) {
    int r0 = rowA + wr*64 + m*16 + fq*4;
    #pragma unroll
    for (int n = 0; n < 4; ++n) {
      int c = rowB + wc*64 + n*16 + fr;
      #pragma unroll
      for (int r = 0; r < 4; ++r)
        outC[(size_t)(r0 + r) * N + c] = acc[m][n][r];
    }
  }
}

// ---------------- flash attention (unchanged from round 6) -----------------
__global__ __launch_bounds__(256, 4)
void attn_fwd(const short* __restrict__ Q, const short* __restrict__ Kt,
              const short* __restrict__ Vt, float* __restrict__ AO,
              const float* __restrict__ temp)
{
  __shared__ short Kl[2][64 * 64];
  __shared__ short Vl[2][64 * 64];
  __shared__ short Pl[4][16 * 64];
  const int tid  = threadIdx.x;
  const int lane = tid & 63;
  const int w    = tid >> 6;
  const int fr   = lane & 15, fq = lane >> 4;
  const int bh = blockIdx.x;
  const int qt = blockIdx.y;
  const int b = bh >> 3, h = bh & 7;
  const size_t base  = (size_t)bh * 2048 * 64;
  const size_t vbase = (size_t)bh * 64 * 2048;
  const int q0 = qt * 64 + w * 16;

  const short* kp = Kt + base;
  const short* vp = Vt + vbase;

  const int srow  = tid >> 3;
  const int scol8 = (tid & 7) * 8;
  const int scolB = (tid & 7) * 16;
  const int sxor  = (srow & 7) << 4;
  const int fxor  = (fr & 7) << 4;

  bf16x8 stK[2], stV[2];
  #define LOAD_TILE(T)                                                              \
    do { int kt_ = (T) * 64;                                                        \
      stK[0] = *(const bf16x8*)(kp + (size_t)(kt_ + srow)      * 64 + scol8);       \
      stK[1] = *(const bf16x8*)(kp + (size_t)(kt_ + 32 + srow) * 64 + scol8);       \
      stV[0] = *(const bf16x8*)(vp + (size_t)srow        * 2048 + kt_ + scol8);     \
      stV[1] = *(const bf16x8*)(vp + (size_t)(32 + srow) * 2048 + kt_ + scol8);     \
    } while (0)
  #define WRITE_TILE(P_)                                                            \
    do {                                                                            \
      *(bf16x8*)((char*)Kl[P_] + (srow)      * 128 + (scolB ^ sxor)) = stK[0];      \
      *(bf16x8*)((char*)Kl[P_] + (32 + srow) * 128 + (scolB ^ sxor)) = stK[1];      \
      *(bf16x8*)((char*)Vl[P_] + (srow)      * 128 + (scolB ^ sxor)) = stV[0];      \
      *(bf16x8*)((char*)Vl[P_] + (32 + srow) * 128 + (scolB ^ sxor)) = stV[1];      \
    } while (0)

  bf16x8 bq[2];
  #pragma unroll
  for (int j = 0; j < 2; ++j)
    bq[j] = *(const bf16x8*)(Q + base + (size_t)(q0 + fr) * 64 + j*32 + fq*8);

  const float Mh = fabsf(temp[h]) * 1.44269504088896f;
  const f32x4 cinit = (f32x4){-Mh, -Mh, -Mh, -Mh};

  f32x4 o[4];
  #pragma unroll
  for (int db = 0; db < 4; ++db) o[db] = (f32x4){0.f, 0.f, 0.f, 0.f};
  float lp = 0.f;

  char* pw = (char*)&Pl[w][0];

  LOAD_TILE(0);
  WRITE_TILE(0);
  LOAD_TILE(1);
  __syncthreads();

  for (int t = 0; t < 32; ++t) {
    const int p = t & 1;
    const char* kl = (const char*)Kl[p];
    const char* vl = (const char*)Vl[p];

    f32x4 s[4];
    #pragma unroll
    for (int nb = 0; nb < 4; ++nb) {
      bf16x8 ak0 = *(const bf16x8*)(kl + (nb*16 + fr) * 128 + ((     fq*16) ^ fxor));
      bf16x8 ak1 = *(const bf16x8*)(kl + (nb*16 + fr) * 128 + ((64 + fq*16) ^ fxor));
      f32x4 z = cinit;
      z = __builtin_amdgcn_mfma_f32_16x16x32_bf16(ak0, bq[0], z, 0, 0, 0);
      z = __builtin_amdgcn_mfma_f32_16x16x32_bf16(ak1, bq[1], z, 0, 0, 0);
      s[nb] = z;
    }
    #pragma unroll
    for (int nb = 0; nb < 4; ++nb)
      #pragma unroll
      for (int r = 0; r < 4; ++r) {
        float pv = exp2f(s[nb][r]);
        s[nb][r] = pv;
        lp += pv;
      }
    #pragma unroll
    for (int nb = 0; nb < 4; ++nb) {
      unsigned lo = cvtpk(s[nb][0], s[nb][1]);
      unsigned hi = cvtpk(s[nb][2], s[nb][3]);
      *(uint2*)(pw + fr * 128 + ((nb*32 + fq*8) ^ fxor)) = make_uint2(lo, hi);
    }
    bf16x8 pa[2];
    #pragma unroll
    for (int j = 0; j < 2; ++j)
      pa[j] = *(const bf16x8*)(pw + fr * 128 + ((j*64 + fq*16) ^ fxor));
    #pragma unroll
    for (int db = 0; db < 4; ++db) {
      bf16x8 bv0 = *(const bf16x8*)(vl + (db*16 + fr) * 128 + ((     fq*16) ^ fxor));
      bf16x8 bv1 = *(const bf16x8*)(vl + (db*16 + fr) * 128 + ((64 + fq*16) ^ fxor));
      o[db] = __builtin_amdgcn_mfma_f32_16x16x32_bf16(pa[0], bv0, o[db], 0, 0, 0);
      o[db] = __builtin_amdgcn_mfma_f32_16x16x32_bf16(pa[1], bv1, o[db], 0, 0, 0);
    }

    __syncthreads();
    if (t < 31) {
      WRITE_TILE(p ^ 1);
      if (t < 30) LOAD_TILE(t + 2);
      __syncthreads();
    }
  }
  #undef LOAD_TILE
  #undef WRITE_TILE

  lp += __shfl_xor(lp, 16);
  lp += __shfl_xor(lp, 32);
  float l4[4];
  #pragma unroll
  for (int r = 0; r < 4; ++r) l4[r] = 1.0f / __shfl(lp, fq*4 + r, 16);
  #pragma unroll
  for (int db = 0; db < 4; ++db)
    #pragma unroll
    for (int r = 0; r < 4; ++r) {
      int row = b * 2048 + q0 + fq*4 + r;
      int col = h * 64 + db*16 + fr;
      AO[(size_t)row * 512 + col] = o[db][r] * l4[r];
    }
}

extern "C" void kernel_launch(void* const* d_in, const int* in_sizes, int n_in,
                              void* d_out, int out_size, void* d_ws, size_t ws_size,
                              hipStream_t stream)
{
  const float* x     = (const float*)d_in[0];   // [4,2048,512] fp32
  const float* w_qkv = (const float*)d_in[1];   // [1536,512]  fp32
  const float* w_out = (const float*)d_in[2];   // [512,512]   fp32
  const float* temp  = (const float*)d_in[3];   // [8,1,1]     fp32
  float* out = (float*)d_out;
  short* ws  = (short*)d_ws;

  const size_t NQ = (size_t)4 * 8 * 2048 * 64;  // 4194304
  short* Qb  = ws;                    // bf16 [b,h,n,64]
  short* Kb  = ws + NQ;               // bf16 [b,h,n,64]
  short* Vtb = ws + 2 * NQ;           // bf16 [b,h,64,n]
  float* AOb = (float*)(ws + 3 * NQ); // fp32 [8192,512]
  // xb/wb alias AOb's space: consumed by gemm_qkv BEFORE attn writes AOb
  short* xb = (short*)AOb;            // bf16 [8192,512]  (8.4MB)
  short* wb = xb + NQ;                // bf16 [1536,512]  (1.6MB) — fits in 16.8MB

  cvt_f32_bf16<<<dim3(2048), 256, 0, stream>>>(x, xb, 524288);
  cvt_f32_bf16<<<dim3(384),  256, 0, stream>>>(w_qkv, wb, 98304);
  gemm_qkv<<<dim3(12, 64), 256, 0, stream>>>(xb, wb, Qb, Kb, Vtb, temp);
  attn_fwd<<<dim3(32, 32), 256, 0, stream>>>(Qb, Kb, Vtb, AOb, temp);
  gemm_out<<<dim3(4, 64), 256, 0, stream>>>(AOb, w_out, out, 8192, 512, 512);
}

// Round 8
// 102.577 us; speedup vs baseline: 2.9476x; 1.2422x over previous
//
#include <hip/hip_runtime.h>
#include <hip/hip_bf16.h>

using bf16x8 = __attribute__((ext_vector_type(8))) short;
using f32x4  = __attribute__((ext_vector_type(4))) float;

__device__ __forceinline__ short f2bf(float f) {
  union { float f; unsigned u; } v; v.f = f;
  unsigned r = (v.u + 0x7FFFu + ((v.u >> 16) & 1u)) >> 16;
  return (short)(unsigned short)r;
}

__device__ __forceinline__ unsigned cvtpk(float lo, float hi) {
  unsigned r;
  asm("v_cvt_pk_bf16_f32 %0, %1, %2" : "=v"(r) : "v"(lo), "v"(hi));
  return r;
}

#define GLLDS(gp, lp) __builtin_amdgcn_global_load_lds(                        \
    (const __attribute__((address_space(1))) void*)(gp),                       \
    (__attribute__((address_space(3))) void*)(lp), 16, 0, 0)

// ---------------- fp32 -> bf16 conversion (8 elems/thread) -----------------
__global__ __launch_bounds__(256)
void cvt_f32_bf16(const float* __restrict__ in, short* __restrict__ out, int n8)
{
  int i = blockIdx.x * 256 + threadIdx.x;
  if (i >= n8) return;
  float4 lo = *(const float4*)(in + (size_t)i * 8);
  float4 hi = *(const float4*)(in + (size_t)i * 8 + 4);
  uint4 r;
  r.x = cvtpk(lo.x, lo.y);
  r.y = cvtpk(lo.z, lo.w);
  r.z = cvtpk(hi.x, hi.y);
  r.w = cvtpk(hi.z, hi.w);
  *(uint4*)(out + (size_t)i * 8) = r;
}

// ---------------- QKV projection (unchanged from round 7) ------------------
__global__ __launch_bounds__(256, 2)
void gemm_qkv(const short* __restrict__ A, const short* __restrict__ B,
              short* __restrict__ outQ, short* __restrict__ outK,
              short* __restrict__ outVt, const float* __restrict__ temp)
{
  __shared__ short As[128 * 32];
  __shared__ short Bs[128 * 32];
  const int Kd = 512;
  const int tid  = threadIdx.x;
  const int lane = tid & 63;
  const int w    = tid >> 6;
  const int wr   = w >> 1, wc = w & 1;
  const int fr   = lane & 15, fq = lane >> 4;
  const int bm = blockIdx.y, bn = blockIdx.x;
  const int rowA = bm * 128, rowB = bn * 128;

  const int lrow   = lane >> 2;
  const int lchunk = ((lane & 3) ^ ((lane >> 3) & 3)) * 8;
  const short* gA0 = A + (size_t)(rowA + w * 32 + lrow) * Kd + lchunk;
  const short* gB0 = B + (size_t)(rowB + w * 32 + lrow) * Kd + lchunk;
  char* lA0 = (char*)As + (w * 32) * 64;
  char* lB0 = (char*)Bs + (w * 32) * 64;
  const int rxor = ((fr >> 1) & 3) << 4;

  f32x4 acc[4][4];
  #pragma unroll
  for (int m = 0; m < 4; ++m)
    #pragma unroll
    for (int n = 0; n < 4; ++n) acc[m][n] = (f32x4){0.f, 0.f, 0.f, 0.f};

  for (int k0 = 0; k0 < Kd; k0 += 32) {
    GLLDS(gA0 + k0,            lA0);
    GLLDS(gA0 + k0 + 16 * Kd,  lA0 + 1024);
    GLLDS(gB0 + k0,            lB0);
    GLLDS(gB0 + k0 + 16 * Kd,  lB0 + 1024);
    __syncthreads();
    bf16x8 afr[4], bfr[4];
    #pragma unroll
    for (int m = 0; m < 4; ++m)
      afr[m] = *(const bf16x8*)((char*)As + (wr*64 + m*16 + fr) * 64 + ((fq*16) ^ rxor));
    #pragma unroll
    for (int n = 0; n < 4; ++n)
      bfr[n] = *(const bf16x8*)((char*)Bs + (wc*64 + n*16 + fr) * 64 + ((fq*16) ^ rxor));
    #pragma unroll
    for (int m = 0; m < 4; ++m)
      #pragma unroll
      for (int n = 0; n < 4; ++n)
        acc[m][n] = __builtin_amdgcn_mfma_f32_16x16x32_bf16(afr[m], bfr[n], acc[m][n], 0, 0, 0);
    __syncthreads();
  }

  const int gc0   = rowB + wc*64;
  const int slice = gc0 >> 6;
  const int t3    = slice >> 3;
  const int h     = slice & 7;
  if (t3 < 2) {
    float scl[4][4];
    const float tval = (t3 == 0) ? temp[h] * 1.44269504088896f : 1.0f;
    #pragma unroll
    for (int m = 0; m < 4; ++m) {
      #pragma unroll
      for (int r = 0; r < 4; ++r) {
        float ss = 0.f;
        #pragma unroll
        for (int n = 0; n < 4; ++n) ss += acc[m][n][r] * acc[m][n][r];
        #pragma unroll
        for (int off = 1; off < 16; off <<= 1) ss += __shfl_xor(ss, off);
        scl[m][r] = tval / fmaxf(sqrtf(ss), 1e-12f);
      }
    }
    short* dst = (t3 == 0) ? outQ : outK;
    #pragma unroll
    for (int m = 0; m < 4; ++m) {
      #pragma unroll
      for (int r = 0; r < 4; ++r) {
        int rg = rowA + wr*64 + m*16 + fq*4 + r;
        int b = rg >> 11, nn = rg & 2047;
        size_t rowoff = ((size_t)(b*8 + h) * 2048 + nn) * 64;
        #pragma unroll
        for (int n = 0; n < 4; ++n)
          dst[rowoff + n*16 + fr] = f2bf(acc[m][n][r] * scl[m][r]);
      }
    }
  } else {
    #pragma unroll
    for (int m = 0; m < 4; ++m) {
      #pragma unroll
      for (int r = 0; r < 4; ++r) {
        int rg = rowA + wr*64 + m*16 + fq*4 + r;
        int b = rg >> 11, nn = rg & 2047;
        #pragma unroll
        for (int n = 0; n < 4; ++n)
          outVt[((size_t)(b*8 + h) * 64 + n*16 + fr) * 2048 + nn] = f2bf(acc[m][n][r]);
      }
    }
  }
}

// ---------------- output projection: bf16 GLLDS GEMM, fp32 out -------------
__global__ __launch_bounds__(256, 2)
void gemm_out(const short* __restrict__ A, const short* __restrict__ B,
              float* __restrict__ outC)
{
  __shared__ short As[128 * 32];
  __shared__ short Bs[128 * 32];
  const int Kd = 512, N = 512;
  const int tid  = threadIdx.x;
  const int lane = tid & 63;
  const int w    = tid >> 6;
  const int wr   = w >> 1, wc = w & 1;
  const int fr   = lane & 15, fq = lane >> 4;
  const int bm = blockIdx.y, bn = blockIdx.x;
  const int rowA = bm * 128, rowB = bn * 128;

  const int lrow   = lane >> 2;
  const int lchunk = ((lane & 3) ^ ((lane >> 3) & 3)) * 8;
  const short* gA0 = A + (size_t)(rowA + w * 32 + lrow) * Kd + lchunk;
  const short* gB0 = B + (size_t)(rowB + w * 32 + lrow) * Kd + lchunk;
  char* lA0 = (char*)As + (w * 32) * 64;
  char* lB0 = (char*)Bs + (w * 32) * 64;
  const int rxor = ((fr >> 1) & 3) << 4;

  f32x4 acc[4][4];
  #pragma unroll
  for (int m = 0; m < 4; ++m)
    #pragma unroll
    for (int n = 0; n < 4; ++n) acc[m][n] = (f32x4){0.f, 0.f, 0.f, 0.f};

  for (int k0 = 0; k0 < Kd; k0 += 32) {
    GLLDS(gA0 + k0,            lA0);
    GLLDS(gA0 + k0 + 16 * Kd,  lA0 + 1024);
    GLLDS(gB0 + k0,            lB0);
    GLLDS(gB0 + k0 + 16 * Kd,  lB0 + 1024);
    __syncthreads();
    bf16x8 afr[4], bfr[4];
    #pragma unroll
    for (int m = 0; m < 4; ++m)
      afr[m] = *(const bf16x8*)((char*)As + (wr*64 + m*16 + fr) * 64 + ((fq*16) ^ rxor));
    #pragma unroll
    for (int n = 0; n < 4; ++n)
      bfr[n] = *(const bf16x8*)((char*)Bs + (wc*64 + n*16 + fr) * 64 + ((fq*16) ^ rxor));
    #pragma unroll
    for (int m = 0; m < 4; ++m)
      #pragma unroll
      for (int n = 0; n < 4; ++n)
        acc[m][n] = __builtin_amdgcn_mfma_f32_16x16x32_bf16(afr[m], bfr[n], acc[m][n], 0, 0, 0);
    __syncthreads();
  }

  #pragma unroll
  for (int m = 0; m < 4; ++m) {
    int r0 = rowA + wr*64 + m*16 + fq*4;
    #pragma unroll
    for (int n = 0; n < 4; ++n) {
      int c = rowB + wc*64 + n*16 + fr;
      #pragma unroll
      for (int r = 0; r < 4; ++r)
        outC[(size_t)(r0 + r) * N + c] = acc[m][n][r];
    }
  }
}

// ---------------- flash attention: 1 barrier/iter, raw exp2, bf16 AO -------
__global__ __launch_bounds__(256, 4)
void attn_fwd(const short* __restrict__ Q, const short* __restrict__ Kt,
              const short* __restrict__ Vt, short* __restrict__ AO,
              const float* __restrict__ temp)
{
  __shared__ short Kl[2][64 * 64];
  __shared__ short Vl[2][64 * 64];
  __shared__ short Pl[4][16 * 64];
  const int tid  = threadIdx.x;
  const int lane = tid & 63;
  const int w    = tid >> 6;
  const int fr   = lane & 15, fq = lane >> 4;
  const int bh = blockIdx.x;          // XCD = bh%8: K/V L2-resident per XCD
  const int qt = blockIdx.y;
  const int b = bh >> 3, h = bh & 7;
  const size_t base  = (size_t)bh * 2048 * 64;
  const size_t vbase = (size_t)bh * 64 * 2048;
  const int q0 = qt * 64 + w * 16;

  const short* kp = Kt + base;
  const short* vp = Vt + vbase;

  const int srow  = tid >> 3;
  const int scol8 = (tid & 7) * 8;
  const int scolB = (tid & 7) * 16;
  const int sxor  = (srow & 7) << 4;
  const int fxor  = (fr & 7) << 4;

  bf16x8 stK[2], stV[2];
  #define LOAD_TILE(T)                                                              \
    do { int kt_ = (T) * 64;                                                        \
      stK[0] = *(const bf16x8*)(kp + (size_t)(kt_ + srow)      * 64 + scol8);       \
      stK[1] = *(const bf16x8*)(kp + (size_t)(kt_ + 32 + srow) * 64 + scol8);       \
      stV[0] = *(const bf16x8*)(vp + (size_t)srow        * 2048 + kt_ + scol8);     \
      stV[1] = *(const bf16x8*)(vp + (size_t)(32 + srow) * 2048 + kt_ + scol8);     \
    } while (0)
  #define WRITE_TILE(P_)                                                            \
    do {                                                                            \
      *(bf16x8*)((char*)Kl[P_] + (srow)      * 128 + (scolB ^ sxor)) = stK[0];      \
      *(bf16x8*)((char*)Kl[P_] + (32 + srow) * 128 + (scolB ^ sxor)) = stK[1];      \
      *(bf16x8*)((char*)Vl[P_] + (srow)      * 128 + (scolB ^ sxor)) = stV[0];      \
      *(bf16x8*)((char*)Vl[P_] + (32 + srow) * 128 + (scolB ^ sxor)) = stV[1];      \
    } while (0)

  bf16x8 bq[2];
  #pragma unroll
  for (int j = 0; j < 2; ++j)
    bq[j] = *(const bf16x8*)(Q + base + (size_t)(q0 + fr) * 64 + j*32 + fq*8);

  // static softmax max (Cauchy-Schwarz): s <= |temp|*log2e, folded via C-operand
  const float Mh = fabsf(temp[h]) * 1.44269504088896f;
  const f32x4 cinit = (f32x4){-Mh, -Mh, -Mh, -Mh};

  f32x4 o[4];
  #pragma unroll
  for (int db = 0; db < 4; ++db) o[db] = (f32x4){0.f, 0.f, 0.f, 0.f};
  float lp = 0.f;

  char* pw = (char*)&Pl[w][0];

  // prologue: buf0=tile0, buf1=tile1, regs=tile2
  LOAD_TILE(0); WRITE_TILE(0);
  LOAD_TILE(1); WRITE_TILE(1);
  LOAD_TILE(2);
  __syncthreads();

  #pragma unroll 2
  for (int t = 0; t < 32; ++t) {
    const int p = t & 1;
    const char* kl = (const char*)Kl[p];
    const char* vl = (const char*)Vl[p];

    f32x4 s[4];
    #pragma unroll
    for (int nb = 0; nb < 4; ++nb) {
      bf16x8 ak0 = *(const bf16x8*)(kl + (nb*16 + fr) * 128 + ((     fq*16) ^ fxor));
      bf16x8 ak1 = *(const bf16x8*)(kl + (nb*16 + fr) * 128 + ((64 + fq*16) ^ fxor));
      f32x4 z = __builtin_amdgcn_mfma_f32_16x16x32_bf16(ak0, bq[0], cinit, 0, 0, 0);
      s[nb]    = __builtin_amdgcn_mfma_f32_16x16x32_bf16(ak1, bq[1], z,     0, 0, 0);
    }
    #pragma unroll
    for (int nb = 0; nb < 4; ++nb)
      #pragma unroll
      for (int r = 0; r < 4; ++r) {
        float pv = __builtin_amdgcn_exp2f(s[nb][r]);   // raw v_exp_f32
        s[nb][r] = pv;
        lp += pv;
      }
    #pragma unroll
    for (int nb = 0; nb < 4; ++nb) {
      unsigned lo = cvtpk(s[nb][0], s[nb][1]);
      unsigned hi = cvtpk(s[nb][2], s[nb][3]);
      *(uint2*)(pw + fr * 128 + ((nb*32 + fq*8) ^ fxor)) = make_uint2(lo, hi);
    }
    bf16x8 pa[2];
    #pragma unroll
    for (int j = 0; j < 2; ++j)
      pa[j] = *(const bf16x8*)(pw + fr * 128 + ((j*64 + fq*16) ^ fxor));
    #pragma unroll
    for (int db = 0; db < 4; ++db) {
      bf16x8 bv0 = *(const bf16x8*)(vl + (db*16 + fr) * 128 + ((     fq*16) ^ fxor));
      bf16x8 bv1 = *(const bf16x8*)(vl + (db*16 + fr) * 128 + ((64 + fq*16) ^ fxor));
      o[db] = __builtin_amdgcn_mfma_f32_16x16x32_bf16(pa[0], bv0, o[db], 0, 0, 0);
      o[db] = __builtin_amdgcn_mfma_f32_16x16x32_bf16(pa[1], bv1, o[db], 0, 0, 0);
    }

    // single barrier per iter: write t+2 into the buffer just read (p)
    if (t < 31) {
      __syncthreads();
      if (t < 30) {
        WRITE_TILE(p);
        if (t < 29) LOAD_TILE(t + 3);
      }
    }
  }
  #undef LOAD_TILE
  #undef WRITE_TILE

  lp += __shfl_xor(lp, 16);
  lp += __shfl_xor(lp, 32);
  float l4[4];
  #pragma unroll
  for (int r = 0; r < 4; ++r) l4[r] = 1.0f / __shfl(lp, fq*4 + r, 16);
  #pragma unroll
  for (int db = 0; db < 4; ++db)
    #pragma unroll
    for (int r = 0; r < 4; ++r) {
      int row = b * 2048 + q0 + fq*4 + r;
      int col = h * 64 + db*16 + fr;
      AO[(size_t)row * 512 + col] = f2bf(o[db][r] * l4[r]);
    }
}

extern "C" void kernel_launch(void* const* d_in, const int* in_sizes, int n_in,
                              void* d_out, int out_size, void* d_ws, size_t ws_size,
                              hipStream_t stream)
{
  const float* x     = (const float*)d_in[0];   // [4,2048,512] fp32
  const float* w_qkv = (const float*)d_in[1];   // [1536,512]  fp32
  const float* w_out = (const float*)d_in[2];   // [512,512]   fp32
  const float* temp  = (const float*)d_in[3];   // [8,1,1]     fp32
  float* out = (float*)d_out;
  short* ws  = (short*)d_ws;

  const size_t NQ = (size_t)4 * 8 * 2048 * 64;  // 4194304
  short* Qb   = ws;            // bf16 [b,h,n,64]
  short* Kb   = ws + NQ;       // bf16 [b,h,n,64]
  short* Vtb  = ws + 2 * NQ;   // bf16 [b,h,64,n]
  short* AO16 = ws + 3 * NQ;   // bf16 [8192,512] attention out (after attn)
  short* xb   = ws + 4 * NQ;   // bf16 x (live during gemm_qkv)
  short* wb   = AO16;          // bf16 w_qkv — aliased, dead before attn writes AO
  short* wob  = xb;            // bf16 w_out — cvt'd after gemm_qkv (xb dead)

  cvt_f32_bf16<<<dim3(2048), 256, 0, stream>>>(x, xb, 524288);
  cvt_f32_bf16<<<dim3(384),  256, 0, stream>>>(w_qkv, wb, 98304);
  gemm_qkv<<<dim3(12, 64), 256, 0, stream>>>(xb, wb, Qb, Kb, Vtb, temp);
  cvt_f32_bf16<<<dim3(128),  256, 0, stream>>>(w_out, wob, 32768);
  attn_fwd<<<dim3(32, 32), 256, 0, stream>>>(Qb, Kb, Vtb, AO16, temp);
  gemm_out<<<dim3(4, 64), 256, 0, stream>>>(AO16, wob, out);
}

// Round 9
// 95.365 us; speedup vs baseline: 3.1705x; 1.0756x over previous
//
#include <hip/hip_runtime.h>
#include <hip/hip_bf16.h>

using bf16x8 = __attribute__((ext_vector_type(8))) short;
using f32x4  = __attribute__((ext_vector_type(4))) float;

__device__ __forceinline__ short f2bf(float f) {
  union { float f; unsigned u; } v; v.f = f;
  unsigned r = (v.u + 0x7FFFu + ((v.u >> 16) & 1u)) >> 16;
  return (short)(unsigned short)r;
}

__device__ __forceinline__ unsigned cvtpk(float lo, float hi) {
  unsigned r;
  asm("v_cvt_pk_bf16_f32 %0, %1, %2" : "=v"(r) : "v"(lo), "v"(hi));
  return r;
}

#define GLLDS(gp, lp) __builtin_amdgcn_global_load_lds(                        \
    (const __attribute__((address_space(1))) void*)(gp),                       \
    (__attribute__((address_space(3))) void*)(lp), 16, 0, 0)

// ---------------- fp32 -> bf16 conversion (8 elems/thread) -----------------
__global__ __launch_bounds__(256)
void cvt_f32_bf16(const float* __restrict__ in, short* __restrict__ out, int n8)
{
  int i = blockIdx.x * 256 + threadIdx.x;
  if (i >= n8) return;
  float4 lo = *(const float4*)(in + (size_t)i * 8);
  float4 hi = *(const float4*)(in + (size_t)i * 8 + 4);
  uint4 r;
  r.x = cvtpk(lo.x, lo.y);
  r.y = cvtpk(lo.z, lo.w);
  r.z = cvtpk(hi.x, hi.y);
  r.w = cvtpk(hi.z, hi.w);
  *(uint4*)(out + (size_t)i * 8) = r;
}

// ---------------- QKV projection (unchanged) -------------------------------
__global__ __launch_bounds__(256, 2)
void gemm_qkv(const short* __restrict__ A, const short* __restrict__ B,
              short* __restrict__ outQ, short* __restrict__ outK,
              short* __restrict__ outVt, const float* __restrict__ temp)
{
  __shared__ short As[128 * 32];
  __shared__ short Bs[128 * 32];
  const int Kd = 512;
  const int tid  = threadIdx.x;
  const int lane = tid & 63;
  const int w    = tid >> 6;
  const int wr   = w >> 1, wc = w & 1;
  const int fr   = lane & 15, fq = lane >> 4;
  const int bm = blockIdx.y, bn = blockIdx.x;
  const int rowA = bm * 128, rowB = bn * 128;

  const int lrow   = lane >> 2;
  const int lchunk = ((lane & 3) ^ ((lane >> 3) & 3)) * 8;
  const short* gA0 = A + (size_t)(rowA + w * 32 + lrow) * Kd + lchunk;
  const short* gB0 = B + (size_t)(rowB + w * 32 + lrow) * Kd + lchunk;
  char* lA0 = (char*)As + (w * 32) * 64;
  char* lB0 = (char*)Bs + (w * 32) * 64;
  const int rxor = ((fr >> 1) & 3) << 4;

  f32x4 acc[4][4];
  #pragma unroll
  for (int m = 0; m < 4; ++m)
    #pragma unroll
    for (int n = 0; n < 4; ++n) acc[m][n] = (f32x4){0.f, 0.f, 0.f, 0.f};

  for (int k0 = 0; k0 < Kd; k0 += 32) {
    GLLDS(gA0 + k0,            lA0);
    GLLDS(gA0 + k0 + 16 * Kd,  lA0 + 1024);
    GLLDS(gB0 + k0,            lB0);
    GLLDS(gB0 + k0 + 16 * Kd,  lB0 + 1024);
    __syncthreads();
    bf16x8 afr[4], bfr[4];
    #pragma unroll
    for (int m = 0; m < 4; ++m)
      afr[m] = *(const bf16x8*)((char*)As + (wr*64 + m*16 + fr) * 64 + ((fq*16) ^ rxor));
    #pragma unroll
    for (int n = 0; n < 4; ++n)
      bfr[n] = *(const bf16x8*)((char*)Bs + (wc*64 + n*16 + fr) * 64 + ((fq*16) ^ rxor));
    #pragma unroll
    for (int m = 0; m < 4; ++m)
      #pragma unroll
      for (int n = 0; n < 4; ++n)
        acc[m][n] = __builtin_amdgcn_mfma_f32_16x16x32_bf16(afr[m], bfr[n], acc[m][n], 0, 0, 0);
    __syncthreads();
  }

  const int gc0   = rowB + wc*64;
  const int slice = gc0 >> 6;
  const int t3    = slice >> 3;
  const int h     = slice & 7;
  if (t3 < 2) {
    float scl[4][4];
    const float tval = (t3 == 0) ? temp[h] * 1.44269504088896f : 1.0f;
    #pragma unroll
    for (int m = 0; m < 4; ++m) {
      #pragma unroll
      for (int r = 0; r < 4; ++r) {
        float ss = 0.f;
        #pragma unroll
        for (int n = 0; n < 4; ++n) ss += acc[m][n][r] * acc[m][n][r];
        #pragma unroll
        for (int off = 1; off < 16; off <<= 1) ss += __shfl_xor(ss, off);
        scl[m][r] = tval / fmaxf(sqrtf(ss), 1e-12f);
      }
    }
    short* dst = (t3 == 0) ? outQ : outK;
    #pragma unroll
    for (int m = 0; m < 4; ++m) {
      #pragma unroll
      for (int r = 0; r < 4; ++r) {
        int rg = rowA + wr*64 + m*16 + fq*4 + r;
        int b = rg >> 11, nn = rg & 2047;
        size_t rowoff = ((size_t)(b*8 + h) * 2048 + nn) * 64;
        #pragma unroll
        for (int n = 0; n < 4; ++n)
          dst[rowoff + n*16 + fr] = f2bf(acc[m][n][r] * scl[m][r]);
      }
    }
  } else {
    #pragma unroll
    for (int m = 0; m < 4; ++m) {
      #pragma unroll
      for (int r = 0; r < 4; ++r) {
        int rg = rowA + wr*64 + m*16 + fq*4 + r;
        int b = rg >> 11, nn = rg & 2047;
        #pragma unroll
        for (int n = 0; n < 4; ++n)
          outVt[((size_t)(b*8 + h) * 64 + n*16 + fr) * 2048 + nn] = f2bf(acc[m][n][r]);
      }
    }
  }
}

// ---------------- output projection (unchanged) ----------------------------
__global__ __launch_bounds__(256, 2)
void gemm_out(const short* __restrict__ A, const short* __restrict__ B,
              float* __restrict__ outC)
{
  __shared__ short As[128 * 32];
  __shared__ short Bs[128 * 32];
  const int Kd = 512, N = 512;
  const int tid  = threadIdx.x;
  const int lane = tid & 63;
  const int w    = tid >> 6;
  const int wr   = w >> 1, wc = w & 1;
  const int fr   = lane & 15, fq = lane >> 4;
  const int bm = blockIdx.y, bn = blockIdx.x;
  const int rowA = bm * 128, rowB = bn * 128;

  const int lrow   = lane >> 2;
  const int lchunk = ((lane & 3) ^ ((lane >> 3) & 3)) * 8;
  const short* gA0 = A + (size_t)(rowA + w * 32 + lrow) * Kd + lchunk;
  const short* gB0 = B + (size_t)(rowB + w * 32 + lrow) * Kd + lchunk;
  char* lA0 = (char*)As + (w * 32) * 64;
  char* lB0 = (char*)Bs + (w * 32) * 64;
  const int rxor = ((fr >> 1) & 3) << 4;

  f32x4 acc[4][4];
  #pragma unroll
  for (int m = 0; m < 4; ++m)
    #pragma unroll
    for (int n = 0; n < 4; ++n) acc[m][n] = (f32x4){0.f, 0.f, 0.f, 0.f};

  for (int k0 = 0; k0 < Kd; k0 += 32) {
    GLLDS(gA0 + k0,            lA0);
    GLLDS(gA0 + k0 + 16 * Kd,  lA0 + 1024);
    GLLDS(gB0 + k0,            lB0);
    GLLDS(gB0 + k0 + 16 * Kd,  lB0 + 1024);
    __syncthreads();
    bf16x8 afr[4], bfr[4];
    #pragma unroll
    for (int m = 0; m < 4; ++m)
      afr[m] = *(const bf16x8*)((char*)As + (wr*64 + m*16 + fr) * 64 + ((fq*16) ^ rxor));
    #pragma unroll
    for (int n = 0; n < 4; ++n)
      bfr[n] = *(const bf16x8*)((char*)Bs + (wc*64 + n*16 + fr) * 64 + ((fq*16) ^ rxor));
    #pragma unroll
    for (int m = 0; m < 4; ++m)
      #pragma unroll
      for (int n = 0; n < 4; ++n)
        acc[m][n] = __builtin_amdgcn_mfma_f32_16x16x32_bf16(afr[m], bfr[n], acc[m][n], 0, 0, 0);
    __syncthreads();
  }

  #pragma unroll
  for (int m = 0; m < 4; ++m) {
    int r0 = rowA + wr*64 + m*16 + fq*4;
    #pragma unroll
    for (int n = 0; n < 4; ++n) {
      int c = rowB + wc*64 + n*16 + fr;
      #pragma unroll
      for (int r = 0; r < 4; ++r)
        outC[(size_t)(r0 + r) * N + c] = acc[m][n][r];
    }
  }
}

// ---------------- flash attention v2: QBLK=128, K/V frags reused 2x --------
// Each wave owns 32 q-rows (2 groups of 16). K- and V-fragments are read from
// LDS ONCE per iter and feed both q-groups' MFMAs -> 1.7x less LDS traffic
// per unit work (LDS BW was the round-8 wall). Grid 32bh x 16qt = 512 blocks,
// 2 blocks/CU; XCD = bh%8 keeps K/V L2-pinned. LDS 48KB.
__global__ __launch_bounds__(256, 2)
void attn_fwd(const short* __restrict__ Q, const short* __restrict__ Kt,
              const short* __restrict__ Vt, short* __restrict__ AO,
              const float* __restrict__ temp)
{
  __shared__ short Kl[2][64 * 64];
  __shared__ short Vl[2][64 * 64];
  __shared__ short Pl[4][2][16 * 64];
  const int tid  = threadIdx.x;
  const int lane = tid & 63;
  const int w    = tid >> 6;
  const int fr   = lane & 15, fq = lane >> 4;
  const int bh = blockIdx.x;          // XCD = bh%8
  const int qt = blockIdx.y;
  const int b = bh >> 3, h = bh & 7;
  const size_t base  = (size_t)bh * 2048 * 64;
  const size_t vbase = (size_t)bh * 64 * 2048;
  const int q0 = qt * 128 + w * 32;   // wave's 32 q-rows

  const short* kp = Kt + base;
  const short* vp = Vt + vbase;

  const int srow  = tid >> 3;
  const int scol8 = (tid & 7) * 8;
  const int scolB = (tid & 7) * 16;
  const int sxor  = (srow & 7) << 4;
  const int fxor  = (fr & 7) << 4;

  bf16x8 stK[2], stV[2];
  #define LOAD_TILE(T)                                                              \
    do { int kt_ = (T) * 64;                                                        \
      stK[0] = *(const bf16x8*)(kp + (size_t)(kt_ + srow)      * 64 + scol8);       \
      stK[1] = *(const bf16x8*)(kp + (size_t)(kt_ + 32 + srow) * 64 + scol8);       \
      stV[0] = *(const bf16x8*)(vp + (size_t)srow        * 2048 + kt_ + scol8);     \
      stV[1] = *(const bf16x8*)(vp + (size_t)(32 + srow) * 2048 + kt_ + scol8);     \
    } while (0)
  #define WRITE_TILE(P_)                                                            \
    do {                                                                            \
      *(bf16x8*)((char*)Kl[P_] + (srow)      * 128 + (scolB ^ sxor)) = stK[0];      \
      *(bf16x8*)((char*)Kl[P_] + (32 + srow) * 128 + (scolB ^ sxor)) = stK[1];      \
      *(bf16x8*)((char*)Vl[P_] + (srow)      * 128 + (scolB ^ sxor)) = stV[0];      \
      *(bf16x8*)((char*)Vl[P_] + (32 + srow) * 128 + (scolB ^ sxor)) = stV[1];      \
    } while (0)

  // Q fragments (B-operand), 2 q-groups
  bf16x8 bq[2][2];
  #pragma unroll
  for (int g = 0; g < 2; ++g)
    #pragma unroll
    for (int j = 0; j < 2; ++j)
      bq[g][j] = *(const bf16x8*)(Q + base + (size_t)(q0 + g*16 + fr) * 64 + j*32 + fq*8);

  // static softmax max (Cauchy-Schwarz): s <= |temp|*log2e
  const float Mh = fabsf(temp[h]) * 1.44269504088896f;
  const f32x4 cinit = (f32x4){-Mh, -Mh, -Mh, -Mh};

  f32x4 o[2][4];
  #pragma unroll
  for (int g = 0; g < 2; ++g)
    #pragma unroll
    for (int db = 0; db < 4; ++db) o[g][db] = (f32x4){0.f, 0.f, 0.f, 0.f};
  float lp0 = 0.f, lp1 = 0.f;

  char* pw0 = (char*)&Pl[w][0][0];
  char* pw1 = (char*)&Pl[w][1][0];

  // prologue: buf0=tile0, buf1=tile1, regs=tile2
  LOAD_TILE(0); WRITE_TILE(0);
  LOAD_TILE(1); WRITE_TILE(1);
  LOAD_TILE(2);
  __syncthreads();

  for (int t = 0; t < 32; ++t) {
    const int p = t & 1;
    const char* kl = (const char*)Kl[p];
    const char* vl = (const char*)Vl[p];

    // QK^T for both q-groups; each K-fragment read once
    f32x4 s[2][4];
    #pragma unroll
    for (int nb = 0; nb < 4; ++nb) {
      bf16x8 ak0 = *(const bf16x8*)(kl + (nb*16 + fr) * 128 + ((     fq*16) ^ fxor));
      bf16x8 ak1 = *(const bf16x8*)(kl + (nb*16 + fr) * 128 + ((64 + fq*16) ^ fxor));
      #pragma unroll
      for (int g = 0; g < 2; ++g) {
        f32x4 z = __builtin_amdgcn_mfma_f32_16x16x32_bf16(ak0, bq[g][0], cinit, 0, 0, 0);
        s[g][nb] = __builtin_amdgcn_mfma_f32_16x16x32_bf16(ak1, bq[g][1], z,     0, 0, 0);
      }
    }
    // softmax + P write, group 0
    #pragma unroll
    for (int nb = 0; nb < 4; ++nb) {
      #pragma unroll
      for (int r = 0; r < 4; ++r) {
        float pv = __builtin_amdgcn_exp2f(s[0][nb][r]);
        s[0][nb][r] = pv;
        lp0 += pv;
      }
      unsigned lo = cvtpk(s[0][nb][0], s[0][nb][1]);
      unsigned hi = cvtpk(s[0][nb][2], s[0][nb][3]);
      *(uint2*)(pw0 + fr * 128 + ((nb*32 + fq*8) ^ fxor)) = make_uint2(lo, hi);
    }
    // softmax + P write, group 1
    #pragma unroll
    for (int nb = 0; nb < 4; ++nb) {
      #pragma unroll
      for (int r = 0; r < 4; ++r) {
        float pv = __builtin_amdgcn_exp2f(s[1][nb][r]);
        s[1][nb][r] = pv;
        lp1 += pv;
      }
      unsigned lo = cvtpk(s[1][nb][0], s[1][nb][1]);
      unsigned hi = cvtpk(s[1][nb][2], s[1][nb][3]);
      *(uint2*)(pw1 + fr * 128 + ((nb*32 + fq*8) ^ fxor)) = make_uint2(lo, hi);
    }
    // P fragments
    bf16x8 pa[2][2];
    #pragma unroll
    for (int j = 0; j < 2; ++j) {
      pa[0][j] = *(const bf16x8*)(pw0 + fr * 128 + ((j*64 + fq*16) ^ fxor));
      pa[1][j] = *(const bf16x8*)(pw1 + fr * 128 + ((j*64 + fq*16) ^ fxor));
    }
    // PV: each V-fragment read once, feeds both q-groups
    #pragma unroll
    for (int db = 0; db < 4; ++db) {
      bf16x8 bv0 = *(const bf16x8*)(vl + (db*16 + fr) * 128 + ((     fq*16) ^ fxor));
      bf16x8 bv1 = *(const bf16x8*)(vl + (db*16 + fr) * 128 + ((64 + fq*16) ^ fxor));
      #pragma unroll
      for (int g = 0; g < 2; ++g) {
        o[g][db] = __builtin_amdgcn_mfma_f32_16x16x32_bf16(pa[g][0], bv0, o[g][db], 0, 0, 0);
        o[g][db] = __builtin_amdgcn_mfma_f32_16x16x32_bf16(pa[g][1], bv1, o[g][db], 0, 0, 0);
      }
    }

    // single barrier per iter; write t+2 into buffer just read
    if (t < 31) {
      __syncthreads();
      if (t < 30) {
        WRITE_TILE(p);
        if (t < 29) LOAD_TILE(t + 3);
      }
    }
  }
  #undef LOAD_TILE
  #undef WRITE_TILE

  // epilogue per q-group
  #pragma unroll
  for (int g = 0; g < 2; ++g) {
    float lpg = g ? lp1 : lp0;
    lpg += __shfl_xor(lpg, 16);
    lpg += __shfl_xor(lpg, 32);
    float l4[4];
    #pragma unroll
    for (int r = 0; r < 4; ++r) l4[r] = 1.0f / __shfl(lpg, fq*4 + r, 16);
    #pragma unroll
    for (int db = 0; db < 4; ++db)
      #pragma unroll
      for (int r = 0; r < 4; ++r) {
        int row = b * 2048 + q0 + g*16 + fq*4 + r;
        int col = h * 64 + db*16 + fr;
        AO[(size_t)row * 512 + col] = f2bf(o[g][db][r] * l4[r]);
      }
  }
}

extern "C" void kernel_launch(void* const* d_in, const int* in_sizes, int n_in,
                              void* d_out, int out_size, void* d_ws, size_t ws_size,
                              hipStream_t stream)
{
  const float* x     = (const float*)d_in[0];   // [4,2048,512] fp32
  const float* w_qkv = (const float*)d_in[1];   // [1536,512]  fp32
  const float* w_out = (const float*)d_in[2];   // [512,512]   fp32
  const float* temp  = (const float*)d_in[3];   // [8,1,1]     fp32
  float* out = (float*)d_out;
  short* ws  = (short*)d_ws;

  const size_t NQ = (size_t)4 * 8 * 2048 * 64;  // 4194304
  short* Qb   = ws;            // bf16 [b,h,n,64]
  short* Kb   = ws + NQ;       // bf16 [b,h,n,64]
  short* Vtb  = ws + 2 * NQ;   // bf16 [b,h,64,n]
  short* AO16 = ws + 3 * NQ;   // bf16 [8192,512] attention out (after attn)
  short* xb   = ws + 4 * NQ;   // bf16 x (live during gemm_qkv)
  short* wb   = AO16;          // bf16 w_qkv — dead before attn writes AO
  short* wob  = xb;            // bf16 w_out — cvt'd after gemm_qkv (xb dead)

  cvt_f32_bf16<<<dim3(2048), 256, 0, stream>>>(x, xb, 524288);
  cvt_f32_bf16<<<dim3(384),  256, 0, stream>>>(w_qkv, wb, 98304);
  gemm_qkv<<<dim3(12, 64), 256, 0, stream>>>(xb, wb, Qb, Kb, Vtb, temp);
  cvt_f32_bf16<<<dim3(128),  256, 0, stream>>>(w_out, wob, 32768);
  attn_fwd<<<dim3(32, 16), 256, 0, stream>>>(Qb, Kb, Vtb, AO16, temp);
  gemm_out<<<dim3(4, 64), 256, 0, stream>>>(AO16, wob, out);
}

// Round 10
// 94.480 us; speedup vs baseline: 3.2002x; 1.0094x over previous
//
#include <hip/hip_runtime.h>
#include <hip/hip_bf16.h>

using bf16x8 = __attribute__((ext_vector_type(8))) short;
using f32x4  = __attribute__((ext_vector_type(4))) float;
using f32x16 = __attribute__((ext_vector_type(16))) float;
using u32x4  = __attribute__((ext_vector_type(4))) unsigned;

__device__ __forceinline__ short f2bf(float f) {
  union { float f; unsigned u; } v; v.f = f;
  unsigned r = (v.u + 0x7FFFu + ((v.u >> 16) & 1u)) >> 16;
  return (short)(unsigned short)r;
}

__device__ __forceinline__ unsigned cvtpk(float lo, float hi) {
  unsigned r;
  asm("v_cvt_pk_bf16_f32 %0, %1, %2" : "=v"(r) : "v"(lo), "v"(hi));
  return r;
}

// swap upper 32 lanes of a with lower 32 lanes of b (one HW op, both updated)
__device__ __forceinline__ void plswap(unsigned &a, unsigned &b) {
  asm("v_permlane32_swap_b32 %0, %1" : "+v"(a), "+v"(b));
}

#define GLLDS(gp, lp) __builtin_amdgcn_global_load_lds(                        \
    (const __attribute__((address_space(1))) void*)(gp),                       \
    (__attribute__((address_space(3))) void*)(lp), 16, 0, 0)

// ---------------- fp32 -> bf16 conversion (8 elems/thread) -----------------
__global__ __launch_bounds__(256)
void cvt_f32_bf16(const float* __restrict__ in, short* __restrict__ out, int n8)
{
  int i = blockIdx.x * 256 + threadIdx.x;
  if (i >= n8) return;
  float4 lo = *(const float4*)(in + (size_t)i * 8);
  float4 hi = *(const float4*)(in + (size_t)i * 8 + 4);
  uint4 r;
  r.x = cvtpk(lo.x, lo.y);
  r.y = cvtpk(lo.z, lo.w);
  r.z = cvtpk(hi.x, hi.y);
  r.w = cvtpk(hi.z, hi.w);
  *(uint4*)(out + (size_t)i * 8) = r;
}

// ---------------- QKV projection (unchanged) -------------------------------
__global__ __launch_bounds__(256, 2)
void gemm_qkv(const short* __restrict__ A, const short* __restrict__ B,
              short* __restrict__ outQ, short* __restrict__ outK,
              short* __restrict__ outVt, const float* __restrict__ temp)
{
  __shared__ short As[128 * 32];
  __shared__ short Bs[128 * 32];
  const int Kd = 512;
  const int tid  = threadIdx.x;
  const int lane = tid & 63;
  const int w    = tid >> 6;
  const int wr   = w >> 1, wc = w & 1;
  const int fr   = lane & 15, fq = lane >> 4;
  const int bm = blockIdx.y, bn = blockIdx.x;
  const int rowA = bm * 128, rowB = bn * 128;

  const int lrow   = lane >> 2;
  const int lchunk = ((lane & 3) ^ ((lane >> 3) & 3)) * 8;
  const short* gA0 = A + (size_t)(rowA + w * 32 + lrow) * Kd + lchunk;
  const short* gB0 = B + (size_t)(rowB + w * 32 + lrow) * Kd + lchunk;
  char* lA0 = (char*)As + (w * 32) * 64;
  char* lB0 = (char*)Bs + (w * 32) * 64;
  const int rxor = ((fr >> 1) & 3) << 4;

  f32x4 acc[4][4];
  #pragma unroll
  for (int m = 0; m < 4; ++m)
    #pragma unroll
    for (int n = 0; n < 4; ++n) acc[m][n] = (f32x4){0.f, 0.f, 0.f, 0.f};

  for (int k0 = 0; k0 < Kd; k0 += 32) {
    GLLDS(gA0 + k0,            lA0);
    GLLDS(gA0 + k0 + 16 * Kd,  lA0 + 1024);
    GLLDS(gB0 + k0,            lB0);
    GLLDS(gB0 + k0 + 16 * Kd,  lB0 + 1024);
    __syncthreads();
    bf16x8 afr[4], bfr[4];
    #pragma unroll
    for (int m = 0; m < 4; ++m)
      afr[m] = *(const bf16x8*)((char*)As + (wr*64 + m*16 + fr) * 64 + ((fq*16) ^ rxor));
    #pragma unroll
    for (int n = 0; n < 4; ++n)
      bfr[n] = *(const bf16x8*)((char*)Bs + (wc*64 + n*16 + fr) * 64 + ((fq*16) ^ rxor));
    #pragma unroll
    for (int m = 0; m < 4; ++m)
      #pragma unroll
      for (int n = 0; n < 4; ++n)
        acc[m][n] = __builtin_amdgcn_mfma_f32_16x16x32_bf16(afr[m], bfr[n], acc[m][n], 0, 0, 0);
    __syncthreads();
  }

  const int gc0   = rowB + wc*64;
  const int slice = gc0 >> 6;
  const int t3    = slice >> 3;
  const int h     = slice & 7;
  if (t3 < 2) {
    float scl[4][4];
    const float tval = (t3 == 0) ? temp[h] * 1.44269504088896f : 1.0f;
    #pragma unroll
    for (int m = 0; m < 4; ++m) {
      #pragma unroll
      for (int r = 0; r < 4; ++r) {
        float ss = 0.f;
        #pragma unroll
        for (int n = 0; n < 4; ++n) ss += acc[m][n][r] * acc[m][n][r];
        #pragma unroll
        for (int off = 1; off < 16; off <<= 1) ss += __shfl_xor(ss, off);
        scl[m][r] = tval / fmaxf(sqrtf(ss), 1e-12f);
      }
    }
    short* dst = (t3 == 0) ? outQ : outK;
    #pragma unroll
    for (int m = 0; m < 4; ++m) {
      #pragma unroll
      for (int r = 0; r < 4; ++r) {
        int rg = rowA + wr*64 + m*16 + fq*4 + r;
        int b = rg >> 11, nn = rg & 2047;
        size_t rowoff = ((size_t)(b*8 + h) * 2048 + nn) * 64;
        #pragma unroll
        for (int n = 0; n < 4; ++n)
          dst[rowoff + n*16 + fr] = f2bf(acc[m][n][r] * scl[m][r]);
      }
    }
  } else {
    #pragma unroll
    for (int m = 0; m < 4; ++m) {
      #pragma unroll
      for (int r = 0; r < 4; ++r) {
        int rg = rowA + wr*64 + m*16 + fq*4 + r;
        int b = rg >> 11, nn = rg & 2047;
        #pragma unroll
        for (int n = 0; n < 4; ++n)
          outVt[((size_t)(b*8 + h) * 64 + n*16 + fr) * 2048 + nn] = f2bf(acc[m][n][r]);
      }
    }
  }
}

// ---------------- output projection (unchanged) ----------------------------
__global__ __launch_bounds__(256, 2)
void gemm_out(const short* __restrict__ A, const short* __restrict__ B,
              float* __restrict__ outC)
{
  __shared__ short As[128 * 32];
  __shared__ short Bs[128 * 32];
  const int Kd = 512, N = 512;
  const int tid  = threadIdx.x;
  const int lane = tid & 63;
  const int w    = tid >> 6;
  const int wr   = w >> 1, wc = w & 1;
  const int fr   = lane & 15, fq = lane >> 4;
  const int bm = blockIdx.y, bn = blockIdx.x;
  const int rowA = bm * 128, rowB = bn * 128;

  const int lrow   = lane >> 2;
  const int lchunk = ((lane & 3) ^ ((lane >> 3) & 3)) * 8;
  const short* gA0 = A + (size_t)(rowA + w * 32 + lrow) * Kd + lchunk;
  const short* gB0 = B + (size_t)(rowB + w * 32 + lrow) * Kd + lchunk;
  char* lA0 = (char*)As + (w * 32) * 64;
  char* lB0 = (char*)Bs + (w * 32) * 64;
  const int rxor = ((fr >> 1) & 3) << 4;

  f32x4 acc[4][4];
  #pragma unroll
  for (int m = 0; m < 4; ++m)
    #pragma unroll
    for (int n = 0; n < 4; ++n) acc[m][n] = (f32x4){0.f, 0.f, 0.f, 0.f};

  for (int k0 = 0; k0 < Kd; k0 += 32) {
    GLLDS(gA0 + k0,            lA0);
    GLLDS(gA0 + k0 + 16 * Kd,  lA0 + 1024);
    GLLDS(gB0 + k0,            lB0);
    GLLDS(gB0 + k0 + 16 * Kd,  lB0 + 1024);
    __syncthreads();
    bf16x8 afr[4], bfr[4];
    #pragma unroll
    for (int m = 0; m < 4; ++m)
      afr[m] = *(const bf16x8*)((char*)As + (wr*64 + m*16 + fr) * 64 + ((fq*16) ^ rxor));
    #pragma unroll
    for (int n = 0; n < 4; ++n)
      bfr[n] = *(const bf16x8*)((char*)Bs + (wc*64 + n*16 + fr) * 64 + ((fq*16) ^ rxor));
    #pragma unroll
    for (int m = 0; m < 4; ++m)
      #pragma unroll
      for (int n = 0; n < 4; ++n)
        acc[m][n] = __builtin_amdgcn_mfma_f32_16x16x32_bf16(afr[m], bfr[n], acc[m][n], 0, 0, 0);
    __syncthreads();
  }

  #pragma unroll
  for (int m = 0; m < 4; ++m) {
    int r0 = rowA + wr*64 + m*16 + fq*4;
    #pragma unroll
    for (int n = 0; n < 4; ++n) {
      int c = rowB + wc*64 + n*16 + fr;
      #pragma unroll
      for (int r = 0; r < 4; ++r)
        outC[(size_t)(r0 + r) * N + c] = acc[m][n][r];
    }
  }
}

// ---------------- flash attention v3: 32x32 MFMA, P in registers -----------
// Swapped QK^T at 32x32: lane's S^T column = one q-row (q=lane&31). P->PV
// A-fragment built in-register: 16 cvt_pk + 8 permlane32_swap per iter/wave,
// zero P LDS traffic. LDS ops/block-iter: 128 -> 80. LDS 33KB, 4 waves/block,
// each wave 32 q-rows; grid 32bh x 16qt, XCD = bh%8 pins K/V in L2.
__global__ __launch_bounds__(256, 2)
void attn_fwd(const short* __restrict__ Q, const short* __restrict__ Kt,
              const short* __restrict__ Vt, short* __restrict__ AO,
              const float* __restrict__ temp)
{
  __shared__ short Kl[2][64 * 64];
  __shared__ short Vl[2][64 * 64];
  __shared__ float Ls[4][32];
  const int tid  = threadIdx.x;
  const int lane = tid & 63;
  const int w    = tid >> 6;
  const int l31  = lane & 31;
  const int hi   = lane >> 5;
  const int bh = blockIdx.x;          // XCD = bh%8
  const int qt = blockIdx.y;
  const int b = bh >> 3, h = bh & 7;
  const size_t base  = (size_t)bh * 2048 * 64;
  const size_t vbase = (size_t)bh * 64 * 2048;
  const int q0 = qt * 128 + w * 32;   // wave's 32 q-rows

  const short* kp = Kt + base;
  const short* vp = Vt + vbase;

  const int srow  = tid >> 3;
  const int scol8 = (tid & 7) * 8;
  const int scolB = (tid & 7) * 16;
  const int sxor  = (srow & 7) << 4;
  const int kswz  = (l31 & 7) << 4;   // frag-read XOR (row&7)<<4

  bf16x8 stK[2], stV[2];
  #define LOAD_TILE(T)                                                              \
    do { int kt_ = (T) * 64;                                                        \
      stK[0] = *(const bf16x8*)(kp + (size_t)(kt_ + srow)      * 64 + scol8);       \
      stK[1] = *(const bf16x8*)(kp + (size_t)(kt_ + 32 + srow) * 64 + scol8);       \
      stV[0] = *(const bf16x8*)(vp + (size_t)srow        * 2048 + kt_ + scol8);     \
      stV[1] = *(const bf16x8*)(vp + (size_t)(32 + srow) * 2048 + kt_ + scol8);     \
    } while (0)
  #define WRITE_TILE(P_)                                                            \
    do {                                                                            \
      *(bf16x8*)((char*)Kl[P_] + (srow)      * 128 + (scolB ^ sxor)) = stK[0];      \
      *(bf16x8*)((char*)Kl[P_] + (32 + srow) * 128 + (scolB ^ sxor)) = stK[1];      \
      *(bf16x8*)((char*)Vl[P_] + (srow)      * 128 + (scolB ^ sxor)) = stV[0];      \
      *(bf16x8*)((char*)Vl[P_] + (32 + srow) * 128 + (scolB ^ sxor)) = stV[1];      \
    } while (0)

  // Q B-frags: lane holds Q[q0+l31][dj*16 + hi*8 .. +7], dj=0..3
  bf16x8 bq[4];
  #pragma unroll
  for (int dj = 0; dj < 4; ++dj)
    bq[dj] = *(const bf16x8*)(Q + base + (size_t)(q0 + l31) * 64 + dj*16 + hi*8);

  // static softmax max (Cauchy-Schwarz): s <= |temp|*log2e
  const float Mh = fabsf(temp[h]) * 1.44269504088896f;
  f32x16 cinit;
  #pragma unroll
  for (int r = 0; r < 16; ++r) cinit[r] = -Mh;

  f32x16 o[2];
  #pragma unroll
  for (int td = 0; td < 2; ++td)
    #pragma unroll
    for (int r = 0; r < 16; ++r) o[td][r] = 0.f;
  float lp = 0.f;   // partial denom of q = l31 (lane-local k subset)

  LOAD_TILE(0); WRITE_TILE(0);
  LOAD_TILE(1); WRITE_TILE(1);
  LOAD_TILE(2);
  __syncthreads();

  for (int t = 0; t < 32; ++t) {
    const int p = t & 1;
    const char* kl = (const char*)Kl[p];
    const char* vl = (const char*)Vl[p];

    // QK^T swapped 32x32: A = K rows (k = tk*32+l31), B = Q rows (q = l31)
    // s[tk] reg r holds S[q=l31][k = tk*32 + (r&3)+8*(r>>2)+4*hi] - Mh
    f32x16 s[2];
    #pragma unroll
    for (int tk = 0; tk < 2; ++tk) {
      f32x16 z = cinit;
      #pragma unroll
      for (int dj = 0; dj < 4; ++dj) {
        bf16x8 ak = *(const bf16x8*)(kl + (tk*32 + l31) * 128 + ((dj*32 + hi*16) ^ kswz));
        z = __builtin_amdgcn_mfma_f32_32x32x16_bf16(ak, bq[dj], z, 0, 0, 0);
      }
      s[tk] = z;
    }
    // P = exp2(s); accumulate lane-partial denom
    #pragma unroll
    for (int tk = 0; tk < 2; ++tk)
      #pragma unroll
      for (int r = 0; r < 16; ++r) {
        float pv = __builtin_amdgcn_exp2f(s[tk][r]);
        s[tk][r] = pv;
        lp += pv;
      }
    // build PV A-frags in-register: per k-16 chunk, 4 cvt_pk + 2 permlane swaps
    bf16x8 pa[4];
    #pragma unroll
    for (int tk = 0; tk < 2; ++tk)
      #pragma unroll
      for (int j = 0; j < 2; ++j) {
        unsigned w0 = cvtpk(s[tk][8*j+0], s[tk][8*j+1]);
        unsigned w2 = cvtpk(s[tk][8*j+4], s[tk][8*j+5]);
        unsigned w1 = cvtpk(s[tk][8*j+2], s[tk][8*j+3]);
        unsigned w3 = cvtpk(s[tk][8*j+6], s[tk][8*j+7]);
        plswap(w0, w2);
        plswap(w1, w3);
        u32x4 pw = {w0, w1, w2, w3};
        pa[tk*2 + j] = __builtin_bit_cast(bf16x8, pw);
      }
    // PV: A = P rows (q = l31), B = V rows (d = td*32+l31)
    #pragma unroll
    for (int td = 0; td < 2; ++td) {
      f32x16 acc = o[td];
      #pragma unroll
      for (int kj = 0; kj < 4; ++kj) {
        bf16x8 bv = *(const bf16x8*)(vl + (td*32 + l31) * 128 + ((kj*32 + hi*16) ^ kswz));
        acc = __builtin_amdgcn_mfma_f32_32x32x16_bf16(pa[kj], bv, acc, 0, 0, 0);
      }
      o[td] = acc;
    }

    if (t < 31) {
      __syncthreads();
      if (t < 30) {
        WRITE_TILE(p);
        if (t < 29) LOAD_TILE(t + 3);
      }
    }
  }
  #undef LOAD_TILE
  #undef WRITE_TILE

  // denom: lanes l31 and l31+32 hold complementary k halves of q=l31
  lp += __shfl_xor(lp, 32);
  if (hi == 0) Ls[w][l31] = 1.0f / lp;   // per-wave region; in-order wave LDS
  #pragma unroll
  for (int td = 0; td < 2; ++td)
    #pragma unroll
    for (int r = 0; r < 16; ++r) {
      int qr = (r & 3) + 8 * (r >> 2) + 4 * hi;   // C/D row (q)
      float li = Ls[w][qr];
      int row = b * 2048 + q0 + qr;
      int col = h * 64 + td * 32 + l31;
      AO[(size_t)row * 512 + col] = f2bf(o[td][r] * li);
    }
}

extern "C" void kernel_launch(void* const* d_in, const int* in_sizes, int n_in,
                              void* d_out, int out_size, void* d_ws, size_t ws_size,
                              hipStream_t stream)
{
  const float* x     = (const float*)d_in[0];   // [4,2048,512] fp32
  const float* w_qkv = (const float*)d_in[1];   // [1536,512]  fp32
  const float* w_out = (const float*)d_in[2];   // [512,512]   fp32
  const float* temp  = (const float*)d_in[3];   // [8,1,1]     fp32
  float* out = (float*)d_out;
  short* ws  = (short*)d_ws;

  const size_t NQ = (size_t)4 * 8 * 2048 * 64;  // 4194304
  short* Qb   = ws;            // bf16 [b,h,n,64]
  short* Kb   = ws + NQ;       // bf16 [b,h,n,64]
  short* Vtb  = ws + 2 * NQ;   // bf16 [b,h,64,n]
  short* AO16 = ws + 3 * NQ;   // bf16 [8192,512] attention out (after attn)
  short* xb   = ws + 4 * NQ;   // bf16 x (live during gemm_qkv)
  short* wb   = AO16;          // bf16 w_qkv — dead before attn writes AO
  short* wob  = xb;            // bf16 w_out — cvt'd after gemm_qkv (xb dead)

  cvt_f32_bf16<<<dim3(2048), 256, 0, stream>>>(x, xb, 524288);
  cvt_f32_bf16<<<dim3(384),  256, 0, stream>>>(w_qkv, wb, 98304);
  gemm_qkv<<<dim3(12, 64), 256, 0, stream>>>(xb, wb, Qb, Kb, Vtb, temp);
  cvt_f32_bf16<<<dim3(128),  256, 0, stream>>>(w_out, wob, 32768);
  attn_fwd<<<dim3(32, 16), 256, 0, stream>>>(Qb, Kb, Vtb, AO16, temp);
  gemm_out<<<dim3(4, 64), 256, 0, stream>>>(AO16, wob, out);
}